// Round 9
// baseline (3133.912 us; speedup 1.0000x reference)
//
#include <hip/hip_runtime.h>

typedef float v4 __attribute__((ext_vector_type(4)));
typedef short bf8 __attribute__((ext_vector_type(8)));  // 8 bf16 in 4 VGPRs
typedef unsigned short u16;
typedef unsigned int u32;

#define DEVI __device__ __forceinline__

namespace {

constexpr int B = 64, C = 64, NPT = 500, NP = 512, T0 = 13, SC = 256, EC = 512, PR = 12;
constexpr size_t SLOTP = (size_t)B * C * NP;  // elems per padded time slice

// byte offsets in d_ws
constexpr size_t SZ_BUF  = 13 * SLOTP * 2;              // 54,525,952 per x buffer (bf16)
constexpr size_t OFF_SK  = 2 * SZ_BUF;                  // f32 [256][B*NPT]
constexpr size_t SZ_SK   = (size_t)SC * B * NPT * 4;    // 32,768,000
constexpr size_t OFF_ST  = OFF_SK + SZ_SK;              // (unused, kept for layout stability)
constexpr size_t OFF_STP = OFF_ST + 1024;               // f32[192] BN params (mean,scl,sh)
constexpr size_t OFF_W1T = OFF_STP + 1024;              // f32[131072]
constexpr size_t OFF_WMX = OFF_W1T + (size_t)131072*4;  // u16[65536]  gconv w bf16
constexpr size_t OFF_WFB = OFF_WMX + (size_t)65536*2;   // u16[65536]  filter w bf16 [l][cp][k128]
constexpr size_t OFF_WGB = OFF_WFB + (size_t)65536*2;   // u16[65536]  gate w bf16
constexpr size_t OFF_SWB = OFF_WGB + (size_t)65536*2;   // u16[131072] skip w bf16 [l][o][c]
constexpr size_t OFF_SPD = OFF_SWB + (size_t)131072*2;  // u16[524288] supports padded bf16
constexpr size_t OFF_PSUM = OFF_SPD + (size_t)524288*2; // f32 [768][128] per-block BN partials
constexpr size_t WS_NEED = OFF_PSUM + (size_t)768*128*4;  // 144,443,392

DEVI float sigm(float x) { return 1.f / (1.f + expf(-x)); }
DEVI float bf2f(u16 u) { u32 x = ((u32)u) << 16; float f; __builtin_memcpy(&f, &x, 4); return f; }
DEVI u16 f2bf(float f) { u32 x; __builtin_memcpy(&x, &f, 4); return (u16)((x + 0x7FFF + ((x >> 16) & 1)) >> 16); }
// A-tile [n512][k128] bf16; XOR picked so 16-consecutive-n fragment reads are 2-way (free),
// transpose writes (n = 8*lane+j) spread over 8 banks.
DEVI int swzA(int n, int k) { int byte = (n << 8) + (k << 1); byte ^= (((n >> 1) ^ (n >> 3)) & 7) << 4; return byte; }
// skip tile [n512][cp64] bf16, same swizzle family
DEVI int swzS(int n, int cp) { int byte = (n << 7) + (cp << 1); byte ^= (((n >> 1) ^ (n >> 3)) & 7) << 4; return byte; }

__global__ void k_debug_ws(float* __restrict__ out, float val) {
  int i = blockIdx.x * 256 + threadIdx.x;
  if (i < B * PR * NPT) out[i] = val;
}

// ---------------- weight repack + param init (every call: ws is re-poisoned) ----------------
__global__ void k_prep(const float* __restrict__ fw, const float* __restrict__ gw,
                       const float* __restrict__ sw, const float* __restrict__ gcw,
                       const float* __restrict__ o1w, const float* __restrict__ sup,
                       u16* __restrict__ WFB, u16* __restrict__ WGB,
                       u16* __restrict__ SWB, u16* __restrict__ WMX,
                       float* __restrict__ W1T, u16* __restrict__ SPD,
                       float* __restrict__ STP) {
  int i = blockIdx.x * 256 + threadIdx.x;
  if (i < 65536) {  // WFB/WGB[l][cp][k=tap*64+c]
    int k = i & 127, cp = (i >> 7) & 63, l = i >> 13;
    int tap = k >> 6, c = k & 63;
    int g = ((l * 64 + cp) * 64 + c) * 2 + tap;
    WFB[i] = f2bf(fw[g]);
    WGB[i] = f2bf(gw[g]);
  }
  int j = i - 65536;
  if (j >= 0 && j < 131072) {  // SWB[l][o][c]
    int c = j & 63, o = (j >> 6) & 255, l = j >> 14;
    SWB[j] = f2bf(sw[(l * 256 + o) * 64 + c]);
  }
  int k2 = i - 196608;
  if (k2 >= 0 && k2 < 65536) WMX[k2] = f2bf(gcw[k2]);  // identical index order
  int m = i - 262144;
  if (m >= 0 && m < 131072) {  // W1T[o][e]
    int e = m & 511, o = m >> 9;
    W1T[m] = o1w[e * 256 + o];
  }
  int sp = i - 393216;
  if (sp >= 0 && sp < 524288) {  // SPD[s][n512][m512] zero-padded bf16
    int mm = sp & 511, n = (sp >> 9) & 511, s = sp >> 18;
    float v = (n < NPT && mm < NPT) ? sup[(size_t)s * NPT * NPT + (size_t)n * NPT + mm] : 0.f;
    SPD[sp] = f2bf(v);
  }
  int q = i - 917504;
  if (q >= 0 && q < 192) STP[q] = (q >= 64 && q < 128) ? 1.f : 0.f;  // identity BN for layer 0
}

// ---------------- enter: [B,12,N,2] -> Xbf[t][b][c][512], t=0 is left-pad, n pad zero ----------------
__global__ void k_enter(const float* __restrict__ in, const float* __restrict__ ew,
                        const float* __restrict__ eb, u16* __restrict__ X) {
  size_t idx = (size_t)blockIdx.x * 256 + threadIdx.x;
  if (idx >= 13 * SLOTP) return;
  int t = (int)(idx / SLOTP);
  size_t r = idx % SLOTP;
  int n = (int)(r % NP);
  int c = (int)((r / NP) % C);
  int b = (int)(r / ((size_t)NP * C));
  float v = 0.f;
  if (n < NPT) {
    v = eb[c];
    if (t > 0) {
      const float* ip = in + (((size_t)b * 12 + (t - 1)) * NPT + n) * 2;
      v += ew[c * 2] * ip[0] + ew[c * 2 + 1] * ip[1];
    }
  }
  X[idx] = f2bf(v);
}

__global__ void k_zero_sk(float* __restrict__ p) {
  size_t i = ((size_t)blockIdx.x * 256 + threadIdx.x) * 4;
  v4 z = {};
  *(v4*)&p[i] = z;
}

// ---------------- MFMA gated conv + fused BN-on-read + fused skip GEMM ----------------
// grid (Tp, B), block (64,8). out XA[c][n] = tanh(F)*sigm(G); skip at t==Tp-1.
__global__ __launch_bounds__(512) void k_gatedconv(
    const u16* __restrict__ X, u16* __restrict__ XA,
    const float* __restrict__ STP,
    const u16* __restrict__ WFl, const float* __restrict__ bfb,
    const u16* __restrict__ WGl, const float* __restrict__ bgb,
    const u16* __restrict__ SWl, const float* __restrict__ sb,
    float* __restrict__ SK, int d, int Tp) {
  __shared__ u16 L[65536];  // 128 KiB
  const int lane = threadIdx.x, w = threadIdx.y;
  const int tid = w * 64 + lane;
  const int t = blockIdx.x, b = blockIdx.y;
  const int lrow = lane & 15, kgrp = lane >> 4;
  const int nbase = w * 64;

  // stage + transpose + BN-on-read: L[n][k=tap*64+c] = bn(X[t+tap*d][b][c][n])
  for (int i = tid; i < 8192; i += 512) {
    int tap = i >> 12;
    int c = (i >> 6) & 63;
    int n0 = (i & 63) * 8;
    const u16* src = &X[(size_t)(t + tap * d) * SLOTP + ((size_t)b * C + c) * NP + n0];
    float mean = STP[c], scl = STP[64 + c], sh = STP[128 + c];
    ushort4 a = *(const ushort4*)src;
    ushort4 a2 = *(const ushort4*)(src + 4);
    u16 vals[8] = {a.x, a.y, a.z, a.w, a2.x, a2.y, a2.z, a2.w};
    int k = tap * 64 + c;
#pragma unroll
    for (int jj = 0; jj < 8; ++jj) {
      int n = n0 + jj;
      L[swzA(n, k) >> 1] = f2bf((bf2f(vals[jj]) - mean) * scl + sh);
    }
  }
  __syncthreads();

  v4 af[4][4], ag[4][4];
#pragma unroll
  for (int a1 = 0; a1 < 4; ++a1)
#pragma unroll
    for (int a2 = 0; a2 < 4; ++a2) { af[a1][a2] = (v4){0.f,0.f,0.f,0.f}; ag[a1][a2] = (v4){0.f,0.f,0.f,0.f}; }

#pragma unroll
  for (int k0 = 0; k0 < 128; k0 += 32) {
    const int kof = k0 + kgrp * 8;
    bf8 Av[4];
#pragma unroll
    for (int nt = 0; nt < 4; ++nt) {
      int n = nbase + nt * 16 + lrow;
      Av[nt] = *(const bf8*)&L[swzA(n, kof) >> 1];
    }
#pragma unroll
    for (int ct = 0; ct < 4; ++ct) {
      bf8 Fw = *(const bf8*)&WFl[(size_t)(ct * 16 + lrow) * 128 + kof];
      bf8 Gw = *(const bf8*)&WGl[(size_t)(ct * 16 + lrow) * 128 + kof];
#pragma unroll
      for (int nt = 0; nt < 4; ++nt) {
        af[nt][ct] = __builtin_amdgcn_mfma_f32_16x16x32_bf16(Av[nt], Fw, af[nt][ct], 0, 0, 0);
        ag[nt][ct] = __builtin_amdgcn_mfma_f32_16x16x32_bf16(Av[nt], Gw, ag[nt][ct], 0, 0, 0);
      }
    }
  }

  // epilogue: activation, store XA[cp][n] (rows n in lane, col cp)
  const size_t xab = (size_t)t * SLOTP + (size_t)b * C * NP;
  ushort4 ovv[4][4];
#pragma unroll
  for (int nt = 0; nt < 4; ++nt) {
    int n0s = nbase + nt * 16 + kgrp * 4;
#pragma unroll
    for (int ct = 0; ct < 4; ++ct) {
      int cp = ct * 16 + lrow;
      float fb = bfb[cp], gb2 = bgb[cp];
      ushort4 ov;
      ov.x = f2bf(tanhf(af[nt][ct][0] + fb) * sigm(ag[nt][ct][0] + gb2));
      ov.y = f2bf(tanhf(af[nt][ct][1] + fb) * sigm(ag[nt][ct][1] + gb2));
      ov.z = f2bf(tanhf(af[nt][ct][2] + fb) * sigm(ag[nt][ct][2] + gb2));
      ov.w = f2bf(tanhf(af[nt][ct][3] + fb) * sigm(ag[nt][ct][3] + gb2));
      ovv[nt][ct] = ov;
      if (n0s < NPT) *(ushort4*)&XA[xab + (size_t)cp * NP + n0s] = ov;
    }
  }

  // fused skip GEMM on the layer's last slice: SK[o][b*N+n] += sb[o] + sum_c sw[o][c]*XA[c][n]
  if (t == Tp - 1) {
    __syncthreads();  // all MFMA reads of L done
#pragma unroll
    for (int nt = 0; nt < 4; ++nt) {
      int n0s = nbase + nt * 16 + kgrp * 4;
#pragma unroll
      for (int ct = 0; ct < 4; ++ct) {
        int cp = ct * 16 + lrow;
        ushort4 ov = ovv[nt][ct];
        L[swzS(n0s + 0, cp) >> 1] = ov.x;
        L[swzS(n0s + 1, cp) >> 1] = ov.y;
        L[swzS(n0s + 2, cp) >> 1] = ov.z;
        L[swzS(n0s + 3, cp) >> 1] = ov.w;
      }
    }
    __syncthreads();
#pragma unroll 1
    for (int ot = 0; ot < 16; ++ot) {
      v4 a[4];
#pragma unroll
      for (int nt = 0; nt < 4; ++nt) a[nt] = (v4){0.f,0.f,0.f,0.f};
#pragma unroll
      for (int k0 = 0; k0 < 64; k0 += 32) {
        const int kof = k0 + kgrp * 8;
        bf8 Bs = *(const bf8*)&SWl[(size_t)(ot * 16 + lrow) * 64 + kof];
#pragma unroll
        for (int nt = 0; nt < 4; ++nt) {
          int n = nbase + nt * 16 + lrow;
          bf8 Av2 = *(const bf8*)&L[swzS(n, kof) >> 1];
          a[nt] = __builtin_amdgcn_mfma_f32_16x16x32_bf16(Av2, Bs, a[nt], 0, 0, 0);
        }
      }
      int o = ot * 16 + lrow;
      float bb = sb[o];
#pragma unroll
      for (int nt = 0; nt < 4; ++nt) {
        int n0s = nbase + nt * 16 + kgrp * 4;
        if (n0s < NPT) {
          float* dst = &SK[(size_t)o * (B * NPT) + (size_t)b * NPT + n0s];
          v4 old = *(const v4*)dst;
          *(v4*)dst = old + a[nt] + bb;
        }
      }
    }
  }
}

// ---------------- MFMA diffusion + mix + BN'd residual + fused BN stats ----------------
// grid (Tp, B), block (64,8); in-place XOUT == XA.
__global__ __launch_bounds__(512) void k_diffmix(
    const u16* __restrict__ XA, const u16* __restrict__ XIN, u16* __restrict__ XOUT,
    const u16* __restrict__ SPD, const u16* __restrict__ WMXl,
    const float* __restrict__ gb, const float* __restrict__ STP,
    float* __restrict__ PSUM, int d) {
  __shared__ u16 G[512 * 128];  // 128 KiB
  __shared__ float sst[128];    // per-channel sum / sumsq
  const int lane = threadIdx.x;
  const int w = threadIdx.y;
  const int tid = w * 64 + lane;
  const int t = blockIdx.x, b = blockIdx.y;
  const int lrow = lane & 15;
  const int kgrp = lane >> 4;
  const int nbase = w * 64;
  const size_t xabase = ((size_t)t * (B * C) + (size_t)b * C) * NP;
  if (tid < 128) sst[tid] = 0.f;

#pragma unroll 1
  for (int s = 0; s < 2; ++s) {
    v4 acc[4][4];
#pragma unroll
    for (int a = 0; a < 4; ++a)
#pragma unroll
      for (int c2 = 0; c2 < 4; ++c2) acc[a][c2] = (v4){0.f, 0.f, 0.f, 0.f};
    const u16* Sb = SPD + (size_t)s * (512 * 512);
#pragma unroll 2
    for (int k0 = 0; k0 < 512; k0 += 32) {
      const int kof = k0 + kgrp * 8;
      bf8 Af[4], Bf[4];
#pragma unroll
      for (int nt = 0; nt < 4; ++nt)
        Af[nt] = *(const bf8*)&Sb[(size_t)(nbase + nt * 16 + lrow) * 512 + kof];
#pragma unroll
      for (int ct = 0; ct < 4; ++ct)
        Bf[ct] = *(const bf8*)&XA[xabase + (size_t)(ct * 16 + lrow) * NP + kof];
#pragma unroll
      for (int nt = 0; nt < 4; ++nt)
#pragma unroll
        for (int ct = 0; ct < 4; ++ct)
          acc[nt][ct] = __builtin_amdgcn_mfma_f32_16x16x32_bf16(Af[nt], Bf[ct], acc[nt][ct], 0, 0, 0);
    }
#pragma unroll
    for (int nt = 0; nt < 4; ++nt)
#pragma unroll
      for (int ct = 0; ct < 4; ++ct)
#pragma unroll
        for (int r = 0; r < 4; ++r) {
          int n = nbase + nt * 16 + kgrp * 4 + r;
          int k = s * 64 + ct * 16 + lrow;
          int byte = (n << 8) + (k << 1);
          byte ^= (n & 7) << 4;
          G[byte >> 1] = f2bf(acc[nt][ct][r]);
        }
  }
  __syncthreads();
  v4 acc2[4][4];
#pragma unroll
  for (int a = 0; a < 4; ++a)
#pragma unroll
    for (int c2 = 0; c2 < 4; ++c2) acc2[a][c2] = (v4){0.f, 0.f, 0.f, 0.f};
#pragma unroll
  for (int k0 = 0; k0 < 128; k0 += 32) {
    const int kof = k0 + kgrp * 8;
    bf8 Af[4], Bf[4];
#pragma unroll
    for (int nt = 0; nt < 4; ++nt) {
      int n = nbase + nt * 16 + lrow;
      int byte = (n << 8) + (kof << 1);
      byte ^= (n & 7) << 4;
      Af[nt] = *(const bf8*)&G[byte >> 1];
    }
#pragma unroll
    for (int ot = 0; ot < 4; ++ot)
      Bf[ot] = *(const bf8*)&WMXl[(size_t)(ot * 16 + lrow) * 128 + kof];
#pragma unroll
    for (int nt = 0; nt < 4; ++nt)
#pragma unroll
      for (int ot = 0; ot < 4; ++ot)
        acc2[nt][ot] = __builtin_amdgcn_mfma_f32_16x16x32_bf16(Af[nt], Bf[ot], acc2[nt][ot], 0, 0, 0);
  }

  // ---- coalesced epilogue: stage acc2 to LDS as [o][n] bf16 (reuses G) ----
  __syncthreads();  // all phase-2 G reads done
#pragma unroll
  for (int nt = 0; nt < 4; ++nt) {
    int n0 = nbase + nt * 16 + kgrp * 4;
#pragma unroll
    for (int ot = 0; ot < 4; ++ot) {
      int o = ot * 16 + lrow;
      int byte = (o << 10) + (n0 << 1);
      byte ^= (o & 7) << 4;
      ushort4 gv;
      gv.x = f2bf(acc2[nt][ot][0]);
      gv.y = f2bf(acc2[nt][ot][1]);
      gv.z = f2bf(acc2[nt][ot][2]);
      gv.w = f2bf(acc2[nt][ot][3]);
      *(ushort4*)&G[byte >> 1] = gv;
    }
  }
  __syncthreads();
  // streaming: per iter i, 512 threads cover rows o = i*8 .. i*8+7 (64 x 16B chunks per row)
  const size_t rbase = ((size_t)(t + d) * (B * C) + (size_t)b * C) * NP;
#pragma unroll 1
  for (int i = 0; i < 8; ++i) {
    int idx = i * 512 + tid;
    int o = idx >> 6;
    int ck = idx & 63;
    int byte = (o << 10) + (ck << 4);
    byte ^= (o & 7) << 4;
    ushort4 g0 = *(const ushort4*)&G[byte >> 1];
    ushort4 g1 = *(const ushort4*)&G[(byte >> 1) + 4];
    int n0 = ck * 8;
    const u16* rp = &XIN[rbase + (size_t)o * NP + n0];
    ushort4 r0 = *(const ushort4*)rp;
    ushort4 r1 = *(const ushort4*)(rp + 4);
    float m = STP[o], sc = STP[64 + o], h = STP[128 + o];
    float bias = gb[o];
    float v[8];
    v[0] = bf2f(g0.x) + bias + (bf2f(r0.x) - m) * sc + h;
    v[1] = bf2f(g0.y) + bias + (bf2f(r0.y) - m) * sc + h;
    v[2] = bf2f(g0.z) + bias + (bf2f(r0.z) - m) * sc + h;
    v[3] = bf2f(g0.w) + bias + (bf2f(r0.w) - m) * sc + h;
    v[4] = bf2f(g1.x) + bias + (bf2f(r1.x) - m) * sc + h;
    v[5] = bf2f(g1.y) + bias + (bf2f(r1.y) - m) * sc + h;
    v[6] = bf2f(g1.z) + bias + (bf2f(r1.z) - m) * sc + h;
    v[7] = bf2f(g1.w) + bias + (bf2f(r1.w) - m) * sc + h;
    ushort4 s0, s1;
    s0.x = f2bf(v[0]); s0.y = f2bf(v[1]); s0.z = f2bf(v[2]); s0.w = f2bf(v[3]);
    s1.x = f2bf(v[4]); s1.y = f2bf(v[5]); s1.z = f2bf(v[6]); s1.w = f2bf(v[7]);
    u16* op = &XOUT[xabase + (size_t)o * NP + n0];
    *(ushort4*)op = s0;
    *(ushort4*)(op + 4) = s1;
    float ls = 0.f, lq = 0.f;
#pragma unroll
    for (int e = 0; e < 8; ++e)
      if (n0 + e < NPT) { ls += v[e]; lq += v[e] * v[e]; }
    atomicAdd(&sst[o], ls);
    atomicAdd(&sst[64 + o], lq);
  }
  __syncthreads();
  if (tid < 128) PSUM[(size_t)(blockIdx.y * gridDim.x + blockIdx.x) * 128 + tid] = sst[tid];
}

// ---------------- reduce per-block partials -> BN params for the next layer ----------------
__global__ void k_bnfin(const float* __restrict__ PSUM, float* __restrict__ stp,
                        const float* __restrict__ gamma, const float* __restrict__ beta,
                        int nblk, int Tp) {
  int c = threadIdx.x;
  if (c < C) {
    double s = 0.0, q = 0.0;
    for (int r = 0; r < nblk; ++r) {
      s += (double)PSUM[(size_t)r * 128 + c];
      q += (double)PSUM[(size_t)r * 128 + 64 + c];
    }
    double cnt = (double)Tp * (double)(B * NPT);
    double m = s / cnt;
    double v = q / cnt - m * m;
    stp[c] = (float)m;
    stp[C + c] = gamma[c] * rsqrtf((float)v + 1e-5f);
    stp[2 * C + c] = beta[c];
  }
}

// ---------------- head 1 ----------------
__global__ __launch_bounds__(256) void k_out1(const float* __restrict__ SK,
                                              const float* __restrict__ W1T,
                                              const float* __restrict__ b1,
                                              u16* __restrict__ H1) {
  __shared__ __align__(16) float ssm[32 * 64];
  __shared__ __align__(16) float wsm[32 * 64];
  const int tx = threadIdx.x, ty = threadIdx.y;
  const int tid = ty * 16 + tx;
  const int p0 = blockIdx.x * 64, e0 = blockIdx.y * 64;
  v4 acc[4] = {};
  for (int o0 = 0; o0 < SC; o0 += 32) {
    __syncthreads();
    for (int i = tid; i < 2048; i += 256) {
      int pp = i & 63, kk = i >> 6;
      ssm[i] = fmaxf(SK[(size_t)(o0 + kk) * (B * NPT) + p0 + pp], 0.f);
      wsm[i] = W1T[(size_t)(o0 + kk) * 512 + e0 + pp];
    }
    __syncthreads();
#pragma unroll
    for (int kk = 0; kk < 32; ++kk) {
      v4 sv = *(const v4*)&ssm[kk * 64 + tx * 4];
      v4 wv = *(const v4*)&wsm[kk * 64 + ty * 4];
#pragma unroll
      for (int r = 0; r < 4; ++r) acc[r] += wv[r] * sv;
    }
  }
#pragma unroll
  for (int r = 0; r < 4; ++r) {
    int e = e0 + ty * 4 + r;
    float bb = b1[e];
    size_t ob = (size_t)e * (B * NPT) + p0 + tx * 4;
#pragma unroll
    for (int q = 0; q < 4; ++q) H1[ob + q] = f2bf(fmaxf(acc[r][q] + bb, 0.f));
  }
}

// ---------------- head 2 ----------------
__global__ __launch_bounds__(256) void k_out2(const u16* __restrict__ H1,
                                              const float* __restrict__ W2,
                                              const float* __restrict__ b2,
                                              float* __restrict__ out) {
  int idx = blockIdx.x * 256 + threadIdx.x;
  if (idx >= B * PR * NPT) return;
  int n = idx % NPT;
  int p12 = (idx / NPT) % PR;
  int b = idx / (NPT * PR);
  size_t p = (size_t)b * NPT + n;
  const float* w = W2 + p12 * EC;
  float acc = b2[p12];
  for (int e = 0; e < EC; e += 4) {
    acc += w[e] * bf2f(H1[(size_t)e * (B * NPT) + p])
         + w[e + 1] * bf2f(H1[(size_t)(e + 1) * (B * NPT) + p])
         + w[e + 2] * bf2f(H1[(size_t)(e + 2) * (B * NPT) + p])
         + w[e + 3] * bf2f(H1[(size_t)(e + 3) * (B * NPT) + p]);
  }
  out[idx] = acc;
}

}  // namespace

extern "C" void kernel_launch(void* const* d_in, const int* in_sizes, int n_in,
                              void* d_out, int out_size, void* d_ws, size_t ws_size,
                              hipStream_t stream) {
  const float* inputs  = (const float*)d_in[0];
  const float* sup     = (const float*)d_in[1];
  const float* enter_w = (const float*)d_in[2];
  const float* enter_b = (const float*)d_in[3];
  const float* filt_w  = (const float*)d_in[4];
  const float* filt_b  = (const float*)d_in[5];
  const float* gate_w  = (const float*)d_in[6];
  const float* gate_b  = (const float*)d_in[7];
  const float* gconv_w = (const float*)d_in[8];
  const float* gconv_b = (const float*)d_in[9];
  const float* skip_w  = (const float*)d_in[10];
  const float* skip_b  = (const float*)d_in[11];
  const float* bn_g    = (const float*)d_in[12];
  const float* bn_b    = (const float*)d_in[13];
  const float* o1w     = (const float*)d_in[14];
  const float* o1b     = (const float*)d_in[15];
  const float* o2w     = (const float*)d_in[16];
  const float* o2b     = (const float*)d_in[17];
  (void)in_sizes; (void)n_in; (void)out_size;

  if (ws_size < WS_NEED) {
    k_debug_ws<<<1500, 256, 0, stream>>>((float*)d_out, (float)(ws_size >> 20));
    return;
  }

  char* base = (char*)d_ws;
  u16*    buf0 = (u16*)base;
  u16*    buf1 = (u16*)(base + SZ_BUF);
  float*  SK   = (float*)(base + OFF_SK);
  float*  STP  = (float*)(base + OFF_STP);
  float*  W1T  = (float*)(base + OFF_W1T);
  u16*    WMX  = (u16*)(base + OFF_WMX);
  u16*    WFB  = (u16*)(base + OFF_WFB);
  u16*    WGB  = (u16*)(base + OFF_WGB);
  u16*    SWB  = (u16*)(base + OFF_SWB);
  u16*    SPD  = (u16*)(base + OFF_SPD);
  float*  PSUM = (float*)(base + OFF_PSUM);

  k_prep<<<3586, 256, 0, stream>>>(filt_w, gate_w, skip_w, gconv_w, o1w, sup,
                                   WFB, WGB, SWB, WMX, W1T, SPD, STP);
  k_enter<<<(int)((13 * SLOTP) / 256), 256, 0, stream>>>(inputs, enter_w, enter_b, buf0);
  k_zero_sk<<<8000, 256, 0, stream>>>(SK);

  static const int dils[8] = {1, 2, 1, 2, 1, 2, 1, 2};
  u16* bufs[2] = {buf0, buf1};
  int T = T0;
  for (int l = 0; l < 8; ++l) {
    const int d = dils[l];
    const int Tp = T - d;
    u16* XIN = bufs[l & 1];
    u16* XAb = bufs[(l + 1) & 1];
    k_gatedconv<<<dim3(Tp, B), dim3(64, 8), 0, stream>>>(
        XIN, XAb, STP, WFB + l * 8192, filt_b + l * 64, WGB + l * 8192, gate_b + l * 64,
        SWB + l * 16384, skip_b + l * 256, SK, d, Tp);
    if (l < 7) {
      k_diffmix<<<dim3(Tp, B), dim3(64, 8), 0, stream>>>(
          XAb, XIN, XAb, SPD, WMX + l * 8192, gconv_b + l * 64, STP, PSUM, d);
      k_bnfin<<<1, 64, 0, stream>>>(PSUM, STP, bn_g + l * 64, bn_b + l * 64, Tp * B, Tp);
    }
    T = Tp;
  }

  u16* H1 = buf1;  // dead after the loop (last x_out landed in buf0)
  k_out1<<<dim3(500, 8), dim3(16, 16), 0, stream>>>(SK, W1T, o1b, H1);
  k_out2<<<1500, 256, 0, stream>>>(H1, o2w, o2b, (float*)d_out);
}

// Round 10
// 2807.267 us; speedup vs baseline: 1.1164x; 1.1164x over previous
//
#include <hip/hip_runtime.h>

typedef float v4 __attribute__((ext_vector_type(4)));
typedef short bf8 __attribute__((ext_vector_type(8)));  // 8 bf16 in 4 VGPRs
typedef unsigned short u16;
typedef unsigned int u32;

#define DEVI __device__ __forceinline__

namespace {

constexpr int B = 64, C = 64, NPT = 500, NP = 512, T0 = 13, SC = 256, EC = 512, PR = 12;
constexpr size_t SLOTP = (size_t)B * C * NP;  // elems per padded time slice

// byte offsets in d_ws
constexpr size_t SZ_BUF  = 13 * SLOTP * 2;              // 54,525,952 per x buffer (bf16)
constexpr size_t OFF_SK  = 2 * SZ_BUF;                  // f32 [256][B*NPT]
constexpr size_t SZ_SK   = (size_t)SC * B * NPT * 4;    // 32,768,000
constexpr size_t OFF_ST  = OFF_SK + SZ_SK;              // (unused, layout stability)
constexpr size_t OFF_STP = OFF_ST + 1024;               // f32[192] BN params (mean,scl,sh)
constexpr size_t OFF_W1T = OFF_STP + 1024;              // f32[131072]
constexpr size_t OFF_WMX = OFF_W1T + (size_t)131072*4;  // u16[65536]  gconv w bf16
constexpr size_t OFF_WFB = OFF_WMX + (size_t)65536*2;   // u16[65536]  filter w bf16 [l][cp][k128]
constexpr size_t OFF_WGB = OFF_WFB + (size_t)65536*2;   // u16[65536]  gate w bf16
constexpr size_t OFF_SWB = OFF_WGB + (size_t)65536*2;   // u16[131072] skip w bf16 [l][o][c]
constexpr size_t OFF_SPD = OFF_SWB + (size_t)131072*2;  // u16[524288] supports padded bf16
constexpr size_t OFF_PSUM = OFF_SPD + (size_t)524288*2; // f32 [768][128] per-block BN partials
constexpr size_t WS_NEED = OFF_PSUM + (size_t)768*128*4;  // 144,443,392

DEVI float sigm(float x) { return 1.f / (1.f + expf(-x)); }
DEVI float bf2f(u16 u) { u32 x = ((u32)u) << 16; float f; __builtin_memcpy(&f, &x, 4); return f; }
DEVI u16 f2bf(float f) { u32 x; __builtin_memcpy(&x, &f, 4); return (u16)((x + 0x7FFF + ((x >> 16) & 1)) >> 16); }
// A-tile [n512][k128] bf16; XOR picked so 16-consecutive-n fragment reads are 2-way (free),
// transpose writes (n = 8*lane+j) spread over 8 banks.
DEVI int swzA(int n, int k) { int byte = (n << 8) + (k << 1); byte ^= (((n >> 1) ^ (n >> 3)) & 7) << 4; return byte; }
// skip tile [n512][cp64] bf16, same swizzle family
DEVI int swzS(int n, int cp) { int byte = (n << 7) + (cp << 1); byte ^= (((n >> 1) ^ (n >> 3)) & 7) << 4; return byte; }

__global__ void k_debug_ws(float* __restrict__ out, float val) {
  int i = blockIdx.x * 256 + threadIdx.x;
  if (i < B * PR * NPT) out[i] = val;
}

// ---------------- weight repack + param init ----------------
__global__ void k_prep(const float* __restrict__ fw, const float* __restrict__ gw,
                       const float* __restrict__ sw, const float* __restrict__ gcw,
                       const float* __restrict__ o1w, const float* __restrict__ sup,
                       u16* __restrict__ WFB, u16* __restrict__ WGB,
                       u16* __restrict__ SWB, u16* __restrict__ WMX,
                       float* __restrict__ W1T, u16* __restrict__ SPD,
                       float* __restrict__ STP) {
  int i = blockIdx.x * 256 + threadIdx.x;
  if (i < 65536) {  // WFB/WGB[l][cp][k=tap*64+c]
    int k = i & 127, cp = (i >> 7) & 63, l = i >> 13;
    int tap = k >> 6, c = k & 63;
    int g = ((l * 64 + cp) * 64 + c) * 2 + tap;
    WFB[i] = f2bf(fw[g]);
    WGB[i] = f2bf(gw[g]);
  }
  int j = i - 65536;
  if (j >= 0 && j < 131072) {  // SWB[l][o][c]
    int c = j & 63, o = (j >> 6) & 255, l = j >> 14;
    SWB[j] = f2bf(sw[(l * 256 + o) * 64 + c]);
  }
  int k2 = i - 196608;
  if (k2 >= 0 && k2 < 65536) WMX[k2] = f2bf(gcw[k2]);  // identical index order
  int m = i - 262144;
  if (m >= 0 && m < 131072) {  // W1T[o][e]
    int e = m & 511, o = m >> 9;
    W1T[m] = o1w[e * 256 + o];
  }
  int sp = i - 393216;
  if (sp >= 0 && sp < 524288) {  // SPD[s][n512][m512] zero-padded bf16
    int mm = sp & 511, n = (sp >> 9) & 511, s = sp >> 18;
    float v = (n < NPT && mm < NPT) ? sup[(size_t)s * NPT * NPT + (size_t)n * NPT + mm] : 0.f;
    SPD[sp] = f2bf(v);
  }
  int q = i - 917504;
  if (q >= 0 && q < 192) STP[q] = (q >= 64 && q < 128) ? 1.f : 0.f;  // identity BN for layer 0
}

// ---------------- enter ----------------
__global__ void k_enter(const float* __restrict__ in, const float* __restrict__ ew,
                        const float* __restrict__ eb, u16* __restrict__ X) {
  size_t idx = (size_t)blockIdx.x * 256 + threadIdx.x;
  if (idx >= 13 * SLOTP) return;
  int t = (int)(idx / SLOTP);
  size_t r = idx % SLOTP;
  int n = (int)(r % NP);
  int c = (int)((r / NP) % C);
  int b = (int)(r / ((size_t)NP * C));
  float v = 0.f;
  if (n < NPT) {
    v = eb[c];
    if (t > 0) {
      const float* ip = in + (((size_t)b * 12 + (t - 1)) * NPT + n) * 2;
      v += ew[c * 2] * ip[0] + ew[c * 2 + 1] * ip[1];
    }
  }
  X[idx] = f2bf(v);
}

__global__ void k_zero_sk(float* __restrict__ p) {
  size_t i = ((size_t)blockIdx.x * 256 + threadIdx.x) * 4;
  v4 z = {};
  *(v4*)&p[i] = z;
}

// ---------------- MFMA gated conv + fused BN-on-read + fused skip GEMM ----------------
// grid (Tp, B), block (64,16) = 1024 threads, 16 waves x 32 n-rows.
__global__ __launch_bounds__(1024) void k_gatedconv(
    const u16* __restrict__ X, u16* __restrict__ XA,
    const float* __restrict__ STP,
    const u16* __restrict__ WFl, const float* __restrict__ bfb,
    const u16* __restrict__ WGl, const float* __restrict__ bgb,
    const u16* __restrict__ SWl, const float* __restrict__ sb,
    float* __restrict__ SK, int d, int Tp) {
  __shared__ u16 L[65536];  // 128 KiB
  const int lane = threadIdx.x, w = threadIdx.y;
  const int tid = w * 64 + lane;
  const int t = blockIdx.x, b = blockIdx.y;
  const int lrow = lane & 15, kgrp = lane >> 4;
  const int nbase = w * 32;

  // stage + transpose + BN-on-read: L[n][k=tap*64+c] = bn(X[t+tap*d][b][c][n])
  for (int i = tid; i < 8192; i += 1024) {
    int tap = i >> 12;
    int c = (i >> 6) & 63;
    int n0 = (i & 63) * 8;
    const u16* src = &X[(size_t)(t + tap * d) * SLOTP + ((size_t)b * C + c) * NP + n0];
    float mean = STP[c], scl = STP[64 + c], sh = STP[128 + c];
    ushort4 a = *(const ushort4*)src;
    ushort4 a2 = *(const ushort4*)(src + 4);
    u16 vals[8] = {a.x, a.y, a.z, a.w, a2.x, a2.y, a2.z, a2.w};
    int k = tap * 64 + c;
#pragma unroll
    for (int jj = 0; jj < 8; ++jj) {
      int n = n0 + jj;
      L[swzA(n, k) >> 1] = f2bf((bf2f(vals[jj]) - mean) * scl + sh);
    }
  }
  __syncthreads();

  v4 af[2][4], ag[2][4];
#pragma unroll
  for (int a1 = 0; a1 < 2; ++a1)
#pragma unroll
    for (int a2 = 0; a2 < 4; ++a2) { af[a1][a2] = (v4){0.f,0.f,0.f,0.f}; ag[a1][a2] = (v4){0.f,0.f,0.f,0.f}; }

#pragma unroll
  for (int k0 = 0; k0 < 128; k0 += 32) {
    const int kof = k0 + kgrp * 8;
    bf8 Av[2];
#pragma unroll
    for (int nt = 0; nt < 2; ++nt) {
      int n = nbase + nt * 16 + lrow;
      Av[nt] = *(const bf8*)&L[swzA(n, kof) >> 1];
    }
#pragma unroll
    for (int ct = 0; ct < 4; ++ct) {
      bf8 Fw = *(const bf8*)&WFl[(size_t)(ct * 16 + lrow) * 128 + kof];
      bf8 Gw = *(const bf8*)&WGl[(size_t)(ct * 16 + lrow) * 128 + kof];
#pragma unroll
      for (int nt = 0; nt < 2; ++nt) {
        af[nt][ct] = __builtin_amdgcn_mfma_f32_16x16x32_bf16(Av[nt], Fw, af[nt][ct], 0, 0, 0);
        ag[nt][ct] = __builtin_amdgcn_mfma_f32_16x16x32_bf16(Av[nt], Gw, ag[nt][ct], 0, 0, 0);
      }
    }
  }

  const size_t xab = (size_t)t * SLOTP + (size_t)b * C * NP;
  ushort4 ovv[2][4];
#pragma unroll
  for (int nt = 0; nt < 2; ++nt) {
    int n0s = nbase + nt * 16 + kgrp * 4;
#pragma unroll
    for (int ct = 0; ct < 4; ++ct) {
      int cp = ct * 16 + lrow;
      float fb = bfb[cp], gb2 = bgb[cp];
      ushort4 ov;
      ov.x = f2bf(tanhf(af[nt][ct][0] + fb) * sigm(ag[nt][ct][0] + gb2));
      ov.y = f2bf(tanhf(af[nt][ct][1] + fb) * sigm(ag[nt][ct][1] + gb2));
      ov.z = f2bf(tanhf(af[nt][ct][2] + fb) * sigm(ag[nt][ct][2] + gb2));
      ov.w = f2bf(tanhf(af[nt][ct][3] + fb) * sigm(ag[nt][ct][3] + gb2));
      ovv[nt][ct] = ov;
      if (n0s < NPT) *(ushort4*)&XA[xab + (size_t)cp * NP + n0s] = ov;
    }
  }

  // fused skip GEMM on the layer's last slice
  if (t == Tp - 1) {
    __syncthreads();  // all MFMA reads of L done
#pragma unroll
    for (int nt = 0; nt < 2; ++nt) {
      int n0s = nbase + nt * 16 + kgrp * 4;
#pragma unroll
      for (int ct = 0; ct < 4; ++ct) {
        int cp = ct * 16 + lrow;
        ushort4 ov = ovv[nt][ct];
        L[swzS(n0s + 0, cp) >> 1] = ov.x;
        L[swzS(n0s + 1, cp) >> 1] = ov.y;
        L[swzS(n0s + 2, cp) >> 1] = ov.z;
        L[swzS(n0s + 3, cp) >> 1] = ov.w;
      }
    }
    __syncthreads();
#pragma unroll 1
    for (int ot = 0; ot < 16; ++ot) {
      v4 a[2];
#pragma unroll
      for (int nt = 0; nt < 2; ++nt) a[nt] = (v4){0.f,0.f,0.f,0.f};
#pragma unroll
      for (int k0 = 0; k0 < 64; k0 += 32) {
        const int kof = k0 + kgrp * 8;
        bf8 Bs = *(const bf8*)&SWl[(size_t)(ot * 16 + lrow) * 64 + kof];
#pragma unroll
        for (int nt = 0; nt < 2; ++nt) {
          int n = nbase + nt * 16 + lrow;
          bf8 Av2 = *(const bf8*)&L[swzS(n, kof) >> 1];
          a[nt] = __builtin_amdgcn_mfma_f32_16x16x32_bf16(Av2, Bs, a[nt], 0, 0, 0);
        }
      }
      int o = ot * 16 + lrow;
      float bb = sb[o];
#pragma unroll
      for (int nt = 0; nt < 2; ++nt) {
        int n0s = nbase + nt * 16 + kgrp * 4;
        if (n0s < NPT) {
          float* dst = &SK[(size_t)o * (B * NPT) + (size_t)b * NPT + n0s];
          v4 old = *(const v4*)dst;
          *(v4*)dst = old + a[nt] + bb;
        }
      }
    }
  }
}

// ---------------- MFMA diffusion + mix + BN'd residual + fused BN stats ----------------
// grid (Tp, B), block (64,16) = 1024 threads; in-place XOUT == XA (single block per (t,b)).
__global__ __launch_bounds__(1024) void k_diffmix(
    const u16* __restrict__ XA, const u16* __restrict__ XIN, u16* __restrict__ XOUT,
    const u16* __restrict__ SPD, const u16* __restrict__ WMXl,
    const float* __restrict__ gb, const float* __restrict__ STP,
    float* __restrict__ PSUM, int d) {
  __shared__ u16 G[512 * 128];  // 128 KiB
  __shared__ float sst[128];
  const int lane = threadIdx.x;
  const int w = threadIdx.y;
  const int tid = w * 64 + lane;
  const int t = blockIdx.x, b = blockIdx.y;
  const int lrow = lane & 15;
  const int kgrp = lane >> 4;
  const int nbase = w * 32;
  const size_t xabase = ((size_t)t * (B * C) + (size_t)b * C) * NP;
  if (tid < 128) sst[tid] = 0.f;

#pragma unroll 1
  for (int s = 0; s < 2; ++s) {
    v4 acc[2][4];
#pragma unroll
    for (int a = 0; a < 2; ++a)
#pragma unroll
      for (int c2 = 0; c2 < 4; ++c2) acc[a][c2] = (v4){0.f, 0.f, 0.f, 0.f};
    const u16* Sb = SPD + (size_t)s * (512 * 512);
#pragma unroll 2
    for (int k0 = 0; k0 < 512; k0 += 32) {
      const int kof = k0 + kgrp * 8;
      bf8 Af[2], Bf[4];
#pragma unroll
      for (int nt = 0; nt < 2; ++nt)
        Af[nt] = *(const bf8*)&Sb[(size_t)(nbase + nt * 16 + lrow) * 512 + kof];
#pragma unroll
      for (int ct = 0; ct < 4; ++ct)
        Bf[ct] = *(const bf8*)&XA[xabase + (size_t)(ct * 16 + lrow) * NP + kof];
#pragma unroll
      for (int nt = 0; nt < 2; ++nt)
#pragma unroll
        for (int ct = 0; ct < 4; ++ct)
          acc[nt][ct] = __builtin_amdgcn_mfma_f32_16x16x32_bf16(Af[nt], Bf[ct], acc[nt][ct], 0, 0, 0);
    }
#pragma unroll
    for (int nt = 0; nt < 2; ++nt)
#pragma unroll
      for (int ct = 0; ct < 4; ++ct)
#pragma unroll
        for (int r = 0; r < 4; ++r) {
          int n = nbase + nt * 16 + kgrp * 4 + r;
          int k = s * 64 + ct * 16 + lrow;
          G[swzA(n, k) >> 1] = f2bf(acc[nt][ct][r]);
        }
  }
  __syncthreads();
  v4 acc2[2][4];
#pragma unroll
  for (int a = 0; a < 2; ++a)
#pragma unroll
    for (int c2 = 0; c2 < 4; ++c2) acc2[a][c2] = (v4){0.f, 0.f, 0.f, 0.f};
#pragma unroll
  for (int k0 = 0; k0 < 128; k0 += 32) {
    const int kof = k0 + kgrp * 8;
    bf8 Af[2], Bf[4];
#pragma unroll
    for (int nt = 0; nt < 2; ++nt) {
      int n = nbase + nt * 16 + lrow;
      Af[nt] = *(const bf8*)&G[swzA(n, kof) >> 1];
    }
#pragma unroll
    for (int ot = 0; ot < 4; ++ot)
      Bf[ot] = *(const bf8*)&WMXl[(size_t)(ot * 16 + lrow) * 128 + kof];
#pragma unroll
    for (int nt = 0; nt < 2; ++nt)
#pragma unroll
      for (int ot = 0; ot < 4; ++ot)
        acc2[nt][ot] = __builtin_amdgcn_mfma_f32_16x16x32_bf16(Af[nt], Bf[ot], acc2[nt][ot], 0, 0, 0);
  }

  // ---- coalesced epilogue: stage acc2 to LDS as [o][n512] bf16 (reuses first 64KB of G) ----
  __syncthreads();  // all phase-2 G reads done
#pragma unroll
  for (int nt = 0; nt < 2; ++nt) {
    int n0 = nbase + nt * 16 + kgrp * 4;
#pragma unroll
    for (int ot = 0; ot < 4; ++ot) {
      int o = ot * 16 + lrow;
      int byte = (o << 10) + (n0 << 1);
      byte ^= (o & 7) << 4;
      ushort4 gv;
      gv.x = f2bf(acc2[nt][ot][0]);
      gv.y = f2bf(acc2[nt][ot][1]);
      gv.z = f2bf(acc2[nt][ot][2]);
      gv.w = f2bf(acc2[nt][ot][3]);
      *(ushort4*)&G[byte >> 1] = gv;
    }
  }
  __syncthreads();
  // streaming: per iter, each wave covers one full o-row (64 x 16B chunks)
  const size_t rbase = ((size_t)(t + d) * (B * C) + (size_t)b * C) * NP;
#pragma unroll 1
  for (int i = 0; i < 4; ++i) {
    int idx = i * 1024 + tid;
    int o = idx >> 6;
    int ck = idx & 63;
    int byte = (o << 10) + (ck << 4);
    byte ^= (o & 7) << 4;
    ushort4 g0 = *(const ushort4*)&G[byte >> 1];
    ushort4 g1 = *(const ushort4*)&G[(byte >> 1) + 4];
    int n0 = ck * 8;
    const u16* rp = &XIN[rbase + (size_t)o * NP + n0];
    ushort4 r0 = *(const ushort4*)rp;
    ushort4 r1 = *(const ushort4*)(rp + 4);
    float m = STP[o], sc = STP[64 + o], h = STP[128 + o];
    float bias = gb[o];
    float v[8];
    v[0] = bf2f(g0.x) + bias + (bf2f(r0.x) - m) * sc + h;
    v[1] = bf2f(g0.y) + bias + (bf2f(r0.y) - m) * sc + h;
    v[2] = bf2f(g0.z) + bias + (bf2f(r0.z) - m) * sc + h;
    v[3] = bf2f(g0.w) + bias + (bf2f(r0.w) - m) * sc + h;
    v[4] = bf2f(g1.x) + bias + (bf2f(r1.x) - m) * sc + h;
    v[5] = bf2f(g1.y) + bias + (bf2f(r1.y) - m) * sc + h;
    v[6] = bf2f(g1.z) + bias + (bf2f(r1.z) - m) * sc + h;
    v[7] = bf2f(g1.w) + bias + (bf2f(r1.w) - m) * sc + h;
    ushort4 s0, s1;
    s0.x = f2bf(v[0]); s0.y = f2bf(v[1]); s0.z = f2bf(v[2]); s0.w = f2bf(v[3]);
    s1.x = f2bf(v[4]); s1.y = f2bf(v[5]); s1.z = f2bf(v[6]); s1.w = f2bf(v[7]);
    u16* op = &XOUT[xabase + (size_t)o * NP + n0];
    *(ushort4*)op = s0;
    *(ushort4*)(op + 4) = s1;
    // BN partial: whole wave shares o -> wave-reduce then one atomic per wave
    float ls = 0.f, lq = 0.f;
#pragma unroll
    for (int e = 0; e < 8; ++e)
      if (n0 + e < NPT) { ls += v[e]; lq += v[e] * v[e]; }
#pragma unroll
    for (int off = 32; off; off >>= 1) {
      ls += __shfl_down(ls, off, 64);
      lq += __shfl_down(lq, off, 64);
    }
    if (lane == 0) {
      atomicAdd(&sst[o], ls);
      atomicAdd(&sst[64 + o], lq);
    }
  }
  __syncthreads();
  if (tid < 128) PSUM[(size_t)(blockIdx.y * gridDim.x + blockIdx.x) * 128 + tid] = sst[tid];
}

// ---------------- parallel reduce PSUM -> BN params ----------------
__global__ __launch_bounds__(1024) void k_bnfin(
    const float* __restrict__ PSUM, float* __restrict__ stp,
    const float* __restrict__ gamma, const float* __restrict__ beta,
    int nblk, int Tp) {
  __shared__ double red[1024];
  int tid = threadIdx.x;
  int c = tid & 127;
  int ch = tid >> 7;  // 0..7
  double s = 0.0;
  for (int r = ch; r < nblk; r += 8) s += (double)PSUM[(size_t)r * 128 + c];
  red[tid] = s;
  __syncthreads();
  if (ch < 4) red[tid] += red[tid + 512];
  __syncthreads();
  if (ch < 2) red[tid] += red[tid + 256];
  __syncthreads();
  if (ch == 0) red[c] = red[c] + red[c + 128];
  __syncthreads();
  if (tid < 64) {
    double cnt = (double)Tp * (double)(B * NPT);
    double m = red[tid] / cnt;
    double v = red[64 + tid] / cnt - m * m;
    stp[tid] = (float)m;
    stp[64 + tid] = gamma[tid] * rsqrtf((float)v + 1e-5f);
    stp[128 + tid] = beta[tid];
  }
}

// ---------------- head 1 ----------------
__global__ __launch_bounds__(256) void k_out1(const float* __restrict__ SK,
                                              const float* __restrict__ W1T,
                                              const float* __restrict__ b1,
                                              u16* __restrict__ H1) {
  __shared__ __align__(16) float ssm[32 * 64];
  __shared__ __align__(16) float wsm[32 * 64];
  const int tx = threadIdx.x, ty = threadIdx.y;
  const int tid = ty * 16 + tx;
  const int p0 = blockIdx.x * 64, e0 = blockIdx.y * 64;
  v4 acc[4] = {};
  for (int o0 = 0; o0 < SC; o0 += 32) {
    __syncthreads();
    for (int i = tid; i < 2048; i += 256) {
      int pp = i & 63, kk = i >> 6;
      ssm[i] = fmaxf(SK[(size_t)(o0 + kk) * (B * NPT) + p0 + pp], 0.f);
      wsm[i] = W1T[(size_t)(o0 + kk) * 512 + e0 + pp];
    }
    __syncthreads();
#pragma unroll
    for (int kk = 0; kk < 32; ++kk) {
      v4 sv = *(const v4*)&ssm[kk * 64 + tx * 4];
      v4 wv = *(const v4*)&wsm[kk * 64 + ty * 4];
#pragma unroll
      for (int r = 0; r < 4; ++r) acc[r] += wv[r] * sv;
    }
  }
#pragma unroll
  for (int r = 0; r < 4; ++r) {
    int e = e0 + ty * 4 + r;
    float bb = b1[e];
    size_t ob = (size_t)e * (B * NPT) + p0 + tx * 4;
#pragma unroll
    for (int q = 0; q < 4; ++q) H1[ob + q] = f2bf(fmaxf(acc[r][q] + bb, 0.f));
  }
}

// ---------------- head 2 ----------------
__global__ __launch_bounds__(256) void k_out2(const u16* __restrict__ H1,
                                              const float* __restrict__ W2,
                                              const float* __restrict__ b2,
                                              float* __restrict__ out) {
  int idx = blockIdx.x * 256 + threadIdx.x;
  if (idx >= B * PR * NPT) return;
  int n = idx % NPT;
  int p12 = (idx / NPT) % PR;
  int b = idx / (NPT * PR);
  size_t p = (size_t)b * NPT + n;
  const float* w = W2 + p12 * EC;
  float acc = b2[p12];
  for (int e = 0; e < EC; e += 4) {
    acc += w[e] * bf2f(H1[(size_t)e * (B * NPT) + p])
         + w[e + 1] * bf2f(H1[(size_t)(e + 1) * (B * NPT) + p])
         + w[e + 2] * bf2f(H1[(size_t)(e + 2) * (B * NPT) + p])
         + w[e + 3] * bf2f(H1[(size_t)(e + 3) * (B * NPT) + p]);
  }
  out[idx] = acc;
}

}  // namespace

extern "C" void kernel_launch(void* const* d_in, const int* in_sizes, int n_in,
                              void* d_out, int out_size, void* d_ws, size_t ws_size,
                              hipStream_t stream) {
  const float* inputs  = (const float*)d_in[0];
  const float* sup     = (const float*)d_in[1];
  const float* enter_w = (const float*)d_in[2];
  const float* enter_b = (const float*)d_in[3];
  const float* filt_w  = (const float*)d_in[4];
  const float* filt_b  = (const float*)d_in[5];
  const float* gate_w  = (const float*)d_in[6];
  const float* gate_b  = (const float*)d_in[7];
  const float* gconv_w = (const float*)d_in[8];
  const float* gconv_b = (const float*)d_in[9];
  const float* skip_w  = (const float*)d_in[10];
  const float* skip_b  = (const float*)d_in[11];
  const float* bn_g    = (const float*)d_in[12];
  const float* bn_b    = (const float*)d_in[13];
  const float* o1w     = (const float*)d_in[14];
  const float* o1b     = (const float*)d_in[15];
  const float* o2w     = (const float*)d_in[16];
  const float* o2b     = (const float*)d_in[17];
  (void)in_sizes; (void)n_in; (void)out_size;

  if (ws_size < WS_NEED) {
    k_debug_ws<<<1500, 256, 0, stream>>>((float*)d_out, (float)(ws_size >> 20));
    return;
  }

  char* base = (char*)d_ws;
  u16*    buf0 = (u16*)base;
  u16*    buf1 = (u16*)(base + SZ_BUF);
  float*  SK   = (float*)(base + OFF_SK);
  float*  STP  = (float*)(base + OFF_STP);
  float*  W1T  = (float*)(base + OFF_W1T);
  u16*    WMX  = (u16*)(base + OFF_WMX);
  u16*    WFB  = (u16*)(base + OFF_WFB);
  u16*    WGB  = (u16*)(base + OFF_WGB);
  u16*    SWB  = (u16*)(base + OFF_SWB);
  u16*    SPD  = (u16*)(base + OFF_SPD);
  float*  PSUM = (float*)(base + OFF_PSUM);

  k_prep<<<3586, 256, 0, stream>>>(filt_w, gate_w, skip_w, gconv_w, o1w, sup,
                                   WFB, WGB, SWB, WMX, W1T, SPD, STP);
  k_enter<<<(int)((13 * SLOTP) / 256), 256, 0, stream>>>(inputs, enter_w, enter_b, buf0);
  k_zero_sk<<<8000, 256, 0, stream>>>(SK);

  static const int dils[8] = {1, 2, 1, 2, 1, 2, 1, 2};
  u16* bufs[2] = {buf0, buf1};
  int T = T0;
  for (int l = 0; l < 8; ++l) {
    const int d = dils[l];
    const int Tp = T - d;
    u16* XIN = bufs[l & 1];
    u16* XAb = bufs[(l + 1) & 1];
    k_gatedconv<<<dim3(Tp, B), dim3(64, 16), 0, stream>>>(
        XIN, XAb, STP, WFB + l * 8192, filt_b + l * 64, WGB + l * 8192, gate_b + l * 64,
        SWB + l * 16384, skip_b + l * 256, SK, d, Tp);
    if (l < 7) {
      k_diffmix<<<dim3(Tp, B), dim3(64, 16), 0, stream>>>(
          XAb, XIN, XAb, SPD, WMX + l * 8192, gconv_b + l * 64, STP, PSUM, d);
      k_bnfin<<<1, 1024, 0, stream>>>(PSUM, STP, bn_g + l * 64, bn_b + l * 64, Tp * B, Tp);
    }
    T = Tp;
  }

  u16* H1 = buf1;  // dead after the loop (last x_out landed in buf0)
  k_out1<<<dim3(500, 8), dim3(16, 16), 0, stream>>>(SK, W1T, o1b, H1);
  k_out2<<<1500, 256, 0, stream>>>(H1, o2w, o2b, (float*)d_out);
}

// Round 11
// 2138.376 us; speedup vs baseline: 1.4656x; 1.3128x over previous
//
#include <hip/hip_runtime.h>

typedef float v4 __attribute__((ext_vector_type(4)));
typedef short bf8 __attribute__((ext_vector_type(8)));  // 8 bf16 in 4 VGPRs
typedef unsigned short u16;
typedef unsigned int u32;

#define DEVI __device__ __forceinline__

namespace {

constexpr int B = 64, C = 64, NPT = 500, NP = 512, T0 = 13, SC = 256, EC = 512, PR = 12;
constexpr size_t SLOTP = (size_t)B * C * NP;  // elems per padded time slice

// byte offsets in d_ws
constexpr size_t SZ_BUF  = 13 * SLOTP * 2;              // 54,525,952 per x buffer (bf16)
constexpr size_t OFF_SK  = 2 * SZ_BUF;                  // f32 [256][B*NPT]
constexpr size_t SZ_SK   = (size_t)SC * B * NPT * 4;    // 32,768,000
constexpr size_t OFF_ST  = OFF_SK + SZ_SK;              // (unused, layout stability)
constexpr size_t OFF_STP = OFF_ST + 1024;               // f32[192] BN params (mean,scl,sh)
constexpr size_t OFF_W1T = OFF_STP + 1024;              // f32[131072]
constexpr size_t OFF_WMX = OFF_W1T + (size_t)131072*4;  // u16[65536]  gconv w bf16
constexpr size_t OFF_WFB = OFF_WMX + (size_t)65536*2;   // u16[65536]  filter w bf16 [l][cp][k128]
constexpr size_t OFF_WGB = OFF_WFB + (size_t)65536*2;   // u16[65536]  gate w bf16
constexpr size_t OFF_SWB = OFF_WGB + (size_t)65536*2;   // u16[131072] skip w bf16 [l][o][c]
constexpr size_t OFF_SPD = OFF_SWB + (size_t)131072*2;  // u16[524288] supports padded bf16
constexpr size_t OFF_PSUM = OFF_SPD + (size_t)524288*2; // f32 [768][128] per-block BN partials
constexpr size_t WS_NEED = OFF_PSUM + (size_t)768*128*4;  // 144,443,392

DEVI float sigm(float x) { return 1.f / (1.f + expf(-x)); }
DEVI float bf2f(u16 u) { u32 x = ((u32)u) << 16; float f; __builtin_memcpy(&f, &x, 4); return f; }
DEVI u16 f2bf(float f) { u32 x; __builtin_memcpy(&x, &f, 4); return (u16)((x + 0x7FFF + ((x >> 16) & 1)) >> 16); }
// A-tile [n512][k128] bf16 (gatedconv)
DEVI int swzA(int n, int k) { int byte = (n << 8) + (k << 1); byte ^= (((n >> 1) ^ (n >> 3)) & 7) << 4; return byte; }
// skip tile [n512][cp64] bf16
DEVI int swzS(int n, int cp) { int byte = (n << 7) + (cp << 1); byte ^= (((n >> 1) ^ (n >> 3)) & 7) << 4; return byte; }
// diffmix: [row64][col512] tiles (1024B rows): row-XOR so 16-row fragment reads are 2-way (free)
DEVI int swzX(int r, int c) { int byte = (r << 10) + (c << 1); byte ^= (r & 7) << 4; return byte; }
// diffmix GS: [n512][k64] (128B rows)
DEVI int swzG(int n, int k) { int byte = (n << 7) + (k << 1); byte ^= (n & 7) << 4; return byte; }

__global__ void k_debug_ws(float* __restrict__ out, float val) {
  int i = blockIdx.x * 256 + threadIdx.x;
  if (i < B * PR * NPT) out[i] = val;
}

// ---------------- weight repack + param init ----------------
__global__ void k_prep(const float* __restrict__ fw, const float* __restrict__ gw,
                       const float* __restrict__ sw, const float* __restrict__ gcw,
                       const float* __restrict__ o1w, const float* __restrict__ sup,
                       u16* __restrict__ WFB, u16* __restrict__ WGB,
                       u16* __restrict__ SWB, u16* __restrict__ WMX,
                       float* __restrict__ W1T, u16* __restrict__ SPD,
                       float* __restrict__ STP) {
  int i = blockIdx.x * 256 + threadIdx.x;
  if (i < 65536) {  // WFB/WGB[l][cp][k=tap*64+c]
    int k = i & 127, cp = (i >> 7) & 63, l = i >> 13;
    int tap = k >> 6, c = k & 63;
    int g = ((l * 64 + cp) * 64 + c) * 2 + tap;
    WFB[i] = f2bf(fw[g]);
    WGB[i] = f2bf(gw[g]);
  }
  int j = i - 65536;
  if (j >= 0 && j < 131072) {  // SWB[l][o][c]
    int c = j & 63, o = (j >> 6) & 255, l = j >> 14;
    SWB[j] = f2bf(sw[(l * 256 + o) * 64 + c]);
  }
  int k2 = i - 196608;
  if (k2 >= 0 && k2 < 65536) WMX[k2] = f2bf(gcw[k2]);  // identical index order
  int m = i - 262144;
  if (m >= 0 && m < 131072) {  // W1T[o][e]
    int e = m & 511, o = m >> 9;
    W1T[m] = o1w[e * 256 + o];
  }
  int sp = i - 393216;
  if (sp >= 0 && sp < 524288) {  // SPD[s][n512][m512] zero-padded bf16
    int mm = sp & 511, n = (sp >> 9) & 511, s = sp >> 18;
    float v = (n < NPT && mm < NPT) ? sup[(size_t)s * NPT * NPT + (size_t)n * NPT + mm] : 0.f;
    SPD[sp] = f2bf(v);
  }
  int q = i - 917504;
  if (q >= 0 && q < 192) STP[q] = (q >= 64 && q < 128) ? 1.f : 0.f;  // identity BN for layer 0
}

// ---------------- enter ----------------
__global__ void k_enter(const float* __restrict__ in, const float* __restrict__ ew,
                        const float* __restrict__ eb, u16* __restrict__ X) {
  size_t idx = (size_t)blockIdx.x * 256 + threadIdx.x;
  if (idx >= 13 * SLOTP) return;
  int t = (int)(idx / SLOTP);
  size_t r = idx % SLOTP;
  int n = (int)(r % NP);
  int c = (int)((r / NP) % C);
  int b = (int)(r / ((size_t)NP * C));
  float v = 0.f;
  if (n < NPT) {
    v = eb[c];
    if (t > 0) {
      const float* ip = in + (((size_t)b * 12 + (t - 1)) * NPT + n) * 2;
      v += ew[c * 2] * ip[0] + ew[c * 2 + 1] * ip[1];
    }
  }
  X[idx] = f2bf(v);
}

__global__ void k_zero_sk(float* __restrict__ p) {
  size_t i = ((size_t)blockIdx.x * 256 + threadIdx.x) * 4;
  v4 z = {};
  *(v4*)&p[i] = z;
}

// ---------------- MFMA gated conv + fused BN-on-read + fused skip GEMM ----------------
// grid (Tp, B), block (64,16) = 1024 threads, 16 waves x 32 n-rows.
__global__ __launch_bounds__(1024) void k_gatedconv(
    const u16* __restrict__ X, u16* __restrict__ XA,
    const float* __restrict__ STP,
    const u16* __restrict__ WFl, const float* __restrict__ bfb,
    const u16* __restrict__ WGl, const float* __restrict__ bgb,
    const u16* __restrict__ SWl, const float* __restrict__ sb,
    float* __restrict__ SK, int d, int Tp) {
  __shared__ u16 L[65536];  // 128 KiB
  const int lane = threadIdx.x, w = threadIdx.y;
  const int tid = w * 64 + lane;
  const int t = blockIdx.x, b = blockIdx.y;
  const int lrow = lane & 15, kgrp = lane >> 4;
  const int nbase = w * 32;

  // stage + transpose + BN-on-read: L[n][k=tap*64+c] = bn(X[t+tap*d][b][c][n])
  for (int i = tid; i < 8192; i += 1024) {
    int tap = i >> 12;
    int c = (i >> 6) & 63;
    int n0 = (i & 63) * 8;
    const u16* src = &X[(size_t)(t + tap * d) * SLOTP + ((size_t)b * C + c) * NP + n0];
    float mean = STP[c], scl = STP[64 + c], sh = STP[128 + c];
    ushort4 a = *(const ushort4*)src;
    ushort4 a2 = *(const ushort4*)(src + 4);
    u16 vals[8] = {a.x, a.y, a.z, a.w, a2.x, a2.y, a2.z, a2.w};
    int k = tap * 64 + c;
#pragma unroll
    for (int jj = 0; jj < 8; ++jj) {
      int n = n0 + jj;
      L[swzA(n, k) >> 1] = f2bf((bf2f(vals[jj]) - mean) * scl + sh);
    }
  }
  __syncthreads();

  v4 af[2][4], ag[2][4];
#pragma unroll
  for (int a1 = 0; a1 < 2; ++a1)
#pragma unroll
    for (int a2 = 0; a2 < 4; ++a2) { af[a1][a2] = (v4){0.f,0.f,0.f,0.f}; ag[a1][a2] = (v4){0.f,0.f,0.f,0.f}; }

#pragma unroll
  for (int k0 = 0; k0 < 128; k0 += 32) {
    const int kof = k0 + kgrp * 8;
    bf8 Av[2];
#pragma unroll
    for (int nt = 0; nt < 2; ++nt) {
      int n = nbase + nt * 16 + lrow;
      Av[nt] = *(const bf8*)&L[swzA(n, kof) >> 1];
    }
#pragma unroll
    for (int ct = 0; ct < 4; ++ct) {
      bf8 Fw = *(const bf8*)&WFl[(size_t)(ct * 16 + lrow) * 128 + kof];
      bf8 Gw = *(const bf8*)&WGl[(size_t)(ct * 16 + lrow) * 128 + kof];
#pragma unroll
      for (int nt = 0; nt < 2; ++nt) {
        af[nt][ct] = __builtin_amdgcn_mfma_f32_16x16x32_bf16(Av[nt], Fw, af[nt][ct], 0, 0, 0);
        ag[nt][ct] = __builtin_amdgcn_mfma_f32_16x16x32_bf16(Av[nt], Gw, ag[nt][ct], 0, 0, 0);
      }
    }
  }

  const size_t xab = (size_t)t * SLOTP + (size_t)b * C * NP;
  ushort4 ovv[2][4];
#pragma unroll
  for (int nt = 0; nt < 2; ++nt) {
    int n0s = nbase + nt * 16 + kgrp * 4;
#pragma unroll
    for (int ct = 0; ct < 4; ++ct) {
      int cp = ct * 16 + lrow;
      float fb = bfb[cp], gb2 = bgb[cp];
      ushort4 ov;
      ov.x = f2bf(tanhf(af[nt][ct][0] + fb) * sigm(ag[nt][ct][0] + gb2));
      ov.y = f2bf(tanhf(af[nt][ct][1] + fb) * sigm(ag[nt][ct][1] + gb2));
      ov.z = f2bf(tanhf(af[nt][ct][2] + fb) * sigm(ag[nt][ct][2] + gb2));
      ov.w = f2bf(tanhf(af[nt][ct][3] + fb) * sigm(ag[nt][ct][3] + gb2));
      ovv[nt][ct] = ov;
      if (n0s < NPT) *(ushort4*)&XA[xab + (size_t)cp * NP + n0s] = ov;
    }
  }

  // fused skip GEMM on the layer's last slice
  if (t == Tp - 1) {
    __syncthreads();  // all MFMA reads of L done
#pragma unroll
    for (int nt = 0; nt < 2; ++nt) {
      int n0s = nbase + nt * 16 + kgrp * 4;
#pragma unroll
      for (int ct = 0; ct < 4; ++ct) {
        int cp = ct * 16 + lrow;
        ushort4 ov = ovv[nt][ct];
        L[swzS(n0s + 0, cp) >> 1] = ov.x;
        L[swzS(n0s + 1, cp) >> 1] = ov.y;
        L[swzS(n0s + 2, cp) >> 1] = ov.z;
        L[swzS(n0s + 3, cp) >> 1] = ov.w;
      }
    }
    __syncthreads();
#pragma unroll 1
    for (int ot = 0; ot < 16; ++ot) {
      v4 a[2];
#pragma unroll
      for (int nt = 0; nt < 2; ++nt) a[nt] = (v4){0.f,0.f,0.f,0.f};
#pragma unroll
      for (int k0 = 0; k0 < 64; k0 += 32) {
        const int kof = k0 + kgrp * 8;
        bf8 Bs = *(const bf8*)&SWl[(size_t)(ot * 16 + lrow) * 64 + kof];
#pragma unroll
        for (int nt = 0; nt < 2; ++nt) {
          int n = nbase + nt * 16 + lrow;
          bf8 Av2 = *(const bf8*)&L[swzS(n, kof) >> 1];
          a[nt] = __builtin_amdgcn_mfma_f32_16x16x32_bf16(Av2, Bs, a[nt], 0, 0, 0);
        }
      }
      int o = ot * 16 + lrow;
      float bb = sb[o];
#pragma unroll
      for (int nt = 0; nt < 2; ++nt) {
        int n0s = nbase + nt * 16 + kgrp * 4;
        if (n0s < NPT) {
          float* dst = &SK[(size_t)o * (B * NPT) + (size_t)b * NPT + n0s];
          v4 old = *(const v4*)dst;
          *(v4*)dst = old + a[nt] + bb;
        }
      }
    }
  }
}

// ---------------- MFMA diffusion + mix + BN'd residual + fused BN stats ----------------
// grid (Tp, B), block (64,8) = 8 waves, M=64/wave. In-place XOUT == XA.
// XA B-operand staged ONCE in LDS (XS, 64KB); per-support G in GS (64KB) with
// phase-2 K=64 partial accumulated into persistent acc2.
__global__ __launch_bounds__(512) void k_diffmix(
    const u16* __restrict__ XA, const u16* __restrict__ XIN, u16* __restrict__ XOUT,
    const u16* __restrict__ SPD, const u16* __restrict__ WMXl,
    const float* __restrict__ gb, const float* __restrict__ STP,
    float* __restrict__ PSUM, int d) {
  __shared__ u16 SH[65536];   // 128KB: XS = SH[0..32767] ([c][m512]), GS = SH+32768 ([n][k64])
  __shared__ float sst[128];
  u16* XS = SH;
  u16* GS = SH + 32768;
  const int lane = threadIdx.x;
  const int w = threadIdx.y;
  const int tid = w * 64 + lane;
  const int t = blockIdx.x, b = blockIdx.y;
  const int lrow = lane & 15;
  const int kgrp = lane >> 4;
  const int nbase = w * 64;
  const size_t xabase = ((size_t)t * (B * C) + (size_t)b * C) * NP;
  if (tid < 128) sst[tid] = 0.f;

  // stage XA tile [c][m0..511] into XS, swizzled; coalesced 1KB rows
  for (int i = tid; i < 4096; i += 512) {
    int c = i >> 6, slot = i & 63;
    const u16* src = &XA[xabase + (size_t)c * NP + slot * 8];
    ushort4 a0 = *(const ushort4*)src;
    ushort4 a1 = *(const ushort4*)(src + 4);
    int byte = swzX(c, slot * 8);
    *(ushort4*)&XS[byte >> 1] = a0;
    *(ushort4*)&XS[(byte >> 1) + 4] = a1;
  }
  __syncthreads();

  v4 acc2[4][4];
#pragma unroll
  for (int a = 0; a < 4; ++a)
#pragma unroll
    for (int c2 = 0; c2 < 4; ++c2) acc2[a][c2] = (v4){0.f, 0.f, 0.f, 0.f};

#pragma unroll 1
  for (int s = 0; s < 2; ++s) {
    v4 acc[4][4];
#pragma unroll
    for (int a = 0; a < 4; ++a)
#pragma unroll
      for (int c2 = 0; c2 < 4; ++c2) acc[a][c2] = (v4){0.f, 0.f, 0.f, 0.f};
    const u16* Sb = SPD + (size_t)s * (512 * 512);
    // phase 1: G_s[n][c] = sum_m S[n][m]*X[c][m]; A (S) pipelined 1 step ahead
    bf8 Ac[4];
#pragma unroll
    for (int nt = 0; nt < 4; ++nt)
      Ac[nt] = *(const bf8*)&Sb[(size_t)(nbase + nt * 16 + lrow) * 512 + kgrp * 8];
#pragma unroll 1
    for (int k0 = 0; k0 < 512; k0 += 32) {
      const int kof = k0 + kgrp * 8;
      bf8 An[4];
      if (k0 + 32 < 512) {
#pragma unroll
        for (int nt = 0; nt < 4; ++nt)
          An[nt] = *(const bf8*)&Sb[(size_t)(nbase + nt * 16 + lrow) * 512 + kof + 32];
      }
      bf8 Bf[4];
#pragma unroll
      for (int ct = 0; ct < 4; ++ct)
        Bf[ct] = *(const bf8*)&XS[swzX(ct * 16 + lrow, kof) >> 1];
#pragma unroll
      for (int nt = 0; nt < 4; ++nt)
#pragma unroll
        for (int ct = 0; ct < 4; ++ct)
          acc[nt][ct] = __builtin_amdgcn_mfma_f32_16x16x32_bf16(Ac[nt], Bf[ct], acc[nt][ct], 0, 0, 0);
#pragma unroll
      for (int nt = 0; nt < 4; ++nt) Ac[nt] = An[nt];
    }
    // dump G_s [n][k=c]
#pragma unroll
    for (int nt = 0; nt < 4; ++nt)
#pragma unroll
      for (int ct = 0; ct < 4; ++ct)
#pragma unroll
        for (int r = 0; r < 4; ++r) {
          int n = nbase + nt * 16 + kgrp * 4 + r;
          int k = ct * 16 + lrow;
          GS[swzG(n, k) >> 1] = f2bf(acc[nt][ct][r]);
        }
    __syncthreads();
    // phase 2 partial: acc2 += G_s * W[:, s*64 .. s*64+63]
#pragma unroll
    for (int k0 = 0; k0 < 64; k0 += 32) {
      const int kof = k0 + kgrp * 8;
      bf8 Af[4], Bw[4];
#pragma unroll
      for (int nt = 0; nt < 4; ++nt)
        Af[nt] = *(const bf8*)&GS[swzG(nbase + nt * 16 + lrow, kof) >> 1];
#pragma unroll
      for (int ot = 0; ot < 4; ++ot)
        Bw[ot] = *(const bf8*)&WMXl[(size_t)(ot * 16 + lrow) * 128 + s * 64 + kof];
#pragma unroll
      for (int nt = 0; nt < 4; ++nt)
#pragma unroll
        for (int ot = 0; ot < 4; ++ot)
          acc2[nt][ot] = __builtin_amdgcn_mfma_f32_16x16x32_bf16(Af[nt], Bw[ot], acc2[nt][ot], 0, 0, 0);
    }
    __syncthreads();  // protect GS for next s (and XS stays intact)
  }

  // ---- coalesced epilogue: stage acc2 -> XS as [o][n512] ----
#pragma unroll
  for (int nt = 0; nt < 4; ++nt) {
    int n0 = nbase + nt * 16 + kgrp * 4;
#pragma unroll
    for (int ot = 0; ot < 4; ++ot) {
      int o = ot * 16 + lrow;
      int byte = swzX(o, n0);
      ushort4 gv;
      gv.x = f2bf(acc2[nt][ot][0]);
      gv.y = f2bf(acc2[nt][ot][1]);
      gv.z = f2bf(acc2[nt][ot][2]);
      gv.w = f2bf(acc2[nt][ot][3]);
      *(ushort4*)&XS[byte >> 1] = gv;
    }
  }
  __syncthreads();
  // streaming: BN'd residual + bias, coalesced 16B; fused BN stats (wave-reduced)
  const size_t rbase = ((size_t)(t + d) * (B * C) + (size_t)b * C) * NP;
#pragma unroll 1
  for (int i = 0; i < 8; ++i) {
    int idx = i * 512 + tid;
    int o = idx >> 6;
    int ck = idx & 63;
    int byte = swzX(o, ck * 8);
    ushort4 g0 = *(const ushort4*)&XS[byte >> 1];
    ushort4 g1 = *(const ushort4*)&XS[(byte >> 1) + 4];
    int n0 = ck * 8;
    const u16* rp = &XIN[rbase + (size_t)o * NP + n0];
    ushort4 r0 = *(const ushort4*)rp;
    ushort4 r1 = *(const ushort4*)(rp + 4);
    float m = STP[o], sc = STP[64 + o], h = STP[128 + o];
    float bias = gb[o];
    float v[8];
    v[0] = bf2f(g0.x) + bias + (bf2f(r0.x) - m) * sc + h;
    v[1] = bf2f(g0.y) + bias + (bf2f(r0.y) - m) * sc + h;
    v[2] = bf2f(g0.z) + bias + (bf2f(r0.z) - m) * sc + h;
    v[3] = bf2f(g0.w) + bias + (bf2f(r0.w) - m) * sc + h;
    v[4] = bf2f(g1.x) + bias + (bf2f(r1.x) - m) * sc + h;
    v[5] = bf2f(g1.y) + bias + (bf2f(r1.y) - m) * sc + h;
    v[6] = bf2f(g1.z) + bias + (bf2f(r1.z) - m) * sc + h;
    v[7] = bf2f(g1.w) + bias + (bf2f(r1.w) - m) * sc + h;
    ushort4 s0, s1;
    s0.x = f2bf(v[0]); s0.y = f2bf(v[1]); s0.z = f2bf(v[2]); s0.w = f2bf(v[3]);
    s1.x = f2bf(v[4]); s1.y = f2bf(v[5]); s1.z = f2bf(v[6]); s1.w = f2bf(v[7]);
    u16* op = &XOUT[xabase + (size_t)o * NP + n0];
    *(ushort4*)op = s0;
    *(ushort4*)(op + 4) = s1;
    float ls = 0.f, lq = 0.f;
#pragma unroll
    for (int e = 0; e < 8; ++e)
      if (n0 + e < NPT) { ls += v[e]; lq += v[e] * v[e]; }
#pragma unroll
    for (int off = 32; off; off >>= 1) {
      ls += __shfl_down(ls, off, 64);
      lq += __shfl_down(lq, off, 64);
    }
    if (lane == 0) {
      atomicAdd(&sst[o], ls);
      atomicAdd(&sst[64 + o], lq);
    }
  }
  __syncthreads();
  if (tid < 128) PSUM[(size_t)(blockIdx.y * gridDim.x + blockIdx.x) * 128 + tid] = sst[tid];
}

// ---------------- parallel reduce PSUM -> BN params ----------------
__global__ __launch_bounds__(1024) void k_bnfin(
    const float* __restrict__ PSUM, float* __restrict__ stp,
    const float* __restrict__ gamma, const float* __restrict__ beta,
    int nblk, int Tp) {
  __shared__ double red[1024];
  int tid = threadIdx.x;
  int c = tid & 127;
  int ch = tid >> 7;  // 0..7
  double s = 0.0;
  for (int r = ch; r < nblk; r += 8) s += (double)PSUM[(size_t)r * 128 + c];
  red[tid] = s;
  __syncthreads();
  if (ch < 4) red[tid] += red[tid + 512];
  __syncthreads();
  if (ch < 2) red[tid] += red[tid + 256];
  __syncthreads();
  if (ch == 0) red[c] = red[c] + red[c + 128];
  __syncthreads();
  if (tid < 64) {
    double cnt = (double)Tp * (double)(B * NPT);
    double m = red[tid] / cnt;
    double v = red[64 + tid] / cnt - m * m;
    stp[tid] = (float)m;
    stp[64 + tid] = gamma[tid] * rsqrtf((float)v + 1e-5f);
    stp[128 + tid] = beta[tid];
  }
}

// ---------------- head 1 ----------------
__global__ __launch_bounds__(256) void k_out1(const float* __restrict__ SK,
                                              const float* __restrict__ W1T,
                                              const float* __restrict__ b1,
                                              u16* __restrict__ H1) {
  __shared__ __align__(16) float ssm[32 * 64];
  __shared__ __align__(16) float wsm[32 * 64];
  const int tx = threadIdx.x, ty = threadIdx.y;
  const int tid = ty * 16 + tx;
  const int p0 = blockIdx.x * 64, e0 = blockIdx.y * 64;
  v4 acc[4] = {};
  for (int o0 = 0; o0 < SC; o0 += 32) {
    __syncthreads();
    for (int i = tid; i < 2048; i += 256) {
      int pp = i & 63, kk = i >> 6;
      ssm[i] = fmaxf(SK[(size_t)(o0 + kk) * (B * NPT) + p0 + pp], 0.f);
      wsm[i] = W1T[(size_t)(o0 + kk) * 512 + e0 + pp];
    }
    __syncthreads();
#pragma unroll
    for (int kk = 0; kk < 32; ++kk) {
      v4 sv = *(const v4*)&ssm[kk * 64 + tx * 4];
      v4 wv = *(const v4*)&wsm[kk * 64 + ty * 4];
#pragma unroll
      for (int r = 0; r < 4; ++r) acc[r] += wv[r] * sv;
    }
  }
#pragma unroll
  for (int r = 0; r < 4; ++r) {
    int e = e0 + ty * 4 + r;
    float bb = b1[e];
    size_t ob = (size_t)e * (B * NPT) + p0 + tx * 4;
#pragma unroll
    for (int q = 0; q < 4; ++q) H1[ob + q] = f2bf(fmaxf(acc[r][q] + bb, 0.f));
  }
}

// ---------------- head 2 ----------------
__global__ __launch_bounds__(256) void k_out2(const u16* __restrict__ H1,
                                              const float* __restrict__ W2,
                                              const float* __restrict__ b2,
                                              float* __restrict__ out) {
  int idx = blockIdx.x * 256 + threadIdx.x;
  if (idx >= B * PR * NPT) return;
  int n = idx % NPT;
  int p12 = (idx / NPT) % PR;
  int b = idx / (NPT * PR);
  size_t p = (size_t)b * NPT + n;
  const float* w = W2 + p12 * EC;
  float acc = b2[p12];
  for (int e = 0; e < EC; e += 4) {
    acc += w[e] * bf2f(H1[(size_t)e * (B * NPT) + p])
         + w[e + 1] * bf2f(H1[(size_t)(e + 1) * (B * NPT) + p])
         + w[e + 2] * bf2f(H1[(size_t)(e + 2) * (B * NPT) + p])
         + w[e + 3] * bf2f(H1[(size_t)(e + 3) * (B * NPT) + p]);
  }
  out[idx] = acc;
}

}  // namespace

extern "C" void kernel_launch(void* const* d_in, const int* in_sizes, int n_in,
                              void* d_out, int out_size, void* d_ws, size_t ws_size,
                              hipStream_t stream) {
  const float* inputs  = (const float*)d_in[0];
  const float* sup     = (const float*)d_in[1];
  const float* enter_w = (const float*)d_in[2];
  const float* enter_b = (const float*)d_in[3];
  const float* filt_w  = (const float*)d_in[4];
  const float* filt_b  = (const float*)d_in[5];
  const float* gate_w  = (const float*)d_in[6];
  const float* gate_b  = (const float*)d_in[7];
  const float* gconv_w = (const float*)d_in[8];
  const float* gconv_b = (const float*)d_in[9];
  const float* skip_w  = (const float*)d_in[10];
  const float* skip_b  = (const float*)d_in[11];
  const float* bn_g    = (const float*)d_in[12];
  const float* bn_b    = (const float*)d_in[13];
  const float* o1w     = (const float*)d_in[14];
  const float* o1b     = (const float*)d_in[15];
  const float* o2w     = (const float*)d_in[16];
  const float* o2b     = (const float*)d_in[17];
  (void)in_sizes; (void)n_in; (void)out_size;

  if (ws_size < WS_NEED) {
    k_debug_ws<<<1500, 256, 0, stream>>>((float*)d_out, (float)(ws_size >> 20));
    return;
  }

  char* base = (char*)d_ws;
  u16*    buf0 = (u16*)base;
  u16*    buf1 = (u16*)(base + SZ_BUF);
  float*  SK   = (float*)(base + OFF_SK);
  float*  STP  = (float*)(base + OFF_STP);
  float*  W1T  = (float*)(base + OFF_W1T);
  u16*    WMX  = (u16*)(base + OFF_WMX);
  u16*    WFB  = (u16*)(base + OFF_WFB);
  u16*    WGB  = (u16*)(base + OFF_WGB);
  u16*    SWB  = (u16*)(base + OFF_SWB);
  u16*    SPD  = (u16*)(base + OFF_SPD);
  float*  PSUM = (float*)(base + OFF_PSUM);

  k_prep<<<3586, 256, 0, stream>>>(filt_w, gate_w, skip_w, gconv_w, o1w, sup,
                                   WFB, WGB, SWB, WMX, W1T, SPD, STP);
  k_enter<<<(int)((13 * SLOTP) / 256), 256, 0, stream>>>(inputs, enter_w, enter_b, buf0);
  k_zero_sk<<<8000, 256, 0, stream>>>(SK);

  static const int dils[8] = {1, 2, 1, 2, 1, 2, 1, 2};
  u16* bufs[2] = {buf0, buf1};
  int T = T0;
  for (int l = 0; l < 8; ++l) {
    const int d = dils[l];
    const int Tp = T - d;
    u16* XIN = bufs[l & 1];
    u16* XAb = bufs[(l + 1) & 1];
    k_gatedconv<<<dim3(Tp, B), dim3(64, 16), 0, stream>>>(
        XIN, XAb, STP, WFB + l * 8192, filt_b + l * 64, WGB + l * 8192, gate_b + l * 64,
        SWB + l * 16384, skip_b + l * 256, SK, d, Tp);
    if (l < 7) {
      k_diffmix<<<dim3(Tp, B), dim3(64, 8), 0, stream>>>(
          XAb, XIN, XAb, SPD, WMX + l * 8192, gconv_b + l * 64, STP, PSUM, d);
      k_bnfin<<<1, 1024, 0, stream>>>(PSUM, STP, bn_g + l * 64, bn_b + l * 64, Tp * B, Tp);
    }
    T = Tp;
  }

  u16* H1 = buf1;  // dead after the loop (last x_out landed in buf0)
  k_out1<<<dim3(500, 8), dim3(16, 16), 0, stream>>>(SK, W1T, o1b, H1);
  k_out2<<<1500, 256, 0, stream>>>(H1, o2w, o2b, (float*)d_out);
}

// Round 12
// 1953.946 us; speedup vs baseline: 1.6039x; 1.0944x over previous
//
#include <hip/hip_runtime.h>

typedef float v4 __attribute__((ext_vector_type(4)));
typedef short bf8 __attribute__((ext_vector_type(8)));  // 8 bf16 in 4 VGPRs
typedef unsigned short u16;
typedef unsigned int u32;

#define DEVI __device__ __forceinline__

namespace {

constexpr int B = 64, C = 64, NPT = 500, NP = 512, T0 = 13, SC = 256, EC = 512, PR = 12;
constexpr size_t SLOTP = (size_t)B * C * NP;  // elems per padded time slice (n-major: [b][n][c])

// byte offsets in d_ws
constexpr size_t SZ_BUF  = 13 * SLOTP * 2;              // 54,525,952 per x buffer (bf16)
constexpr size_t OFF_SK  = 2 * SZ_BUF;                  // f32 [256][B*NPT]
constexpr size_t SZ_SK   = (size_t)SC * B * NPT * 4;    // 32,768,000
constexpr size_t OFF_ST  = OFF_SK + SZ_SK;              // (spare)
constexpr size_t OFF_STP = OFF_ST + 1024;               // f32[192] BN params (mean,scl,sh)
constexpr size_t OFF_W1T = OFF_STP + 1024;              // f32[131072]
constexpr size_t OFF_WMX = OFF_W1T + (size_t)131072*4;  // u16[65536]  gconv w bf16
constexpr size_t OFF_WFB = OFF_WMX + (size_t)65536*2;   // u16[65536]  filter w bf16 [l][cp][k128]
constexpr size_t OFF_WGB = OFF_WFB + (size_t)65536*2;   // u16[65536]  gate w bf16
constexpr size_t OFF_SWB = OFF_WGB + (size_t)65536*2;   // u16[131072] skip w bf16 [l][o][c]
constexpr size_t OFF_SPD = OFF_SWB + (size_t)131072*2;  // u16[524288] supports padded bf16
constexpr size_t OFF_PSUM = OFF_SPD + (size_t)524288*2; // f32 [768][128] per-block BN partials
constexpr size_t OFF_WFP = OFF_PSUM + (size_t)768*128*4;  // u16[8192] folded filter w (cur layer)
constexpr size_t OFF_WGP = OFF_WFP + 16384;               // u16[8192] folded gate w
constexpr size_t OFF_BFP = OFF_WGP + 16384;               // f32[64] folded filter bias
constexpr size_t OFF_BGP = OFF_BFP + 256;                 // f32[64] folded gate bias
constexpr size_t WS_NEED = OFF_BGP + 256;                 // ~144.5 MB

DEVI float sigm(float x) { return 1.f / (1.f + expf(-x)); }
DEVI float bf2f(u16 u) { u32 x = ((u32)u) << 16; float f; __builtin_memcpy(&f, &x, 4); return f; }
DEVI u16 f2bf(float f) { u32 x; __builtin_memcpy(&x, &f, 4); return (u16)((x + 0x7FFF + ((x >> 16) & 1)) >> 16); }
// [row64][col512] (1024B rows): row-XOR so 16-row fragment reads are 2-way (free)
DEVI int swzX(int r, int c) { int byte = (r << 10) + (c << 1); byte ^= (r & 7) << 4; return byte; }
// [n512][k64] (128B rows)
DEVI int swzG(int n, int k) { int byte = (n << 7) + (k << 1); byte ^= (n & 7) << 4; return byte; }

__global__ void k_debug_ws(float* __restrict__ out, float val) {
  int i = blockIdx.x * 256 + threadIdx.x;
  if (i < B * PR * NPT) out[i] = val;
}

// ---------------- weight repack + param init ----------------
__global__ void k_prep(const float* __restrict__ fw, const float* __restrict__ gw,
                       const float* __restrict__ sw, const float* __restrict__ gcw,
                       const float* __restrict__ o1w, const float* __restrict__ sup,
                       const float* __restrict__ fbias, const float* __restrict__ gbias,
                       u16* __restrict__ WFB, u16* __restrict__ WGB,
                       u16* __restrict__ SWB, u16* __restrict__ WMX,
                       float* __restrict__ W1T, u16* __restrict__ SPD,
                       float* __restrict__ STP,
                       u16* __restrict__ WFP, u16* __restrict__ WGP,
                       float* __restrict__ BFP, float* __restrict__ BGP) {
  int i = blockIdx.x * 256 + threadIdx.x;
  if (i < 65536) {  // WFB/WGB[l][cp][k=tap*64+c]
    int k = i & 127, cp = (i >> 7) & 63, l = i >> 13;
    int tap = k >> 6, c = k & 63;
    int g = ((l * 64 + cp) * 64 + c) * 2 + tap;
    WFB[i] = f2bf(fw[g]);
    WGB[i] = f2bf(gw[g]);
  }
  int j = i - 65536;
  if (j >= 0 && j < 131072) {  // SWB[l][o][c]
    int c = j & 63, o = (j >> 6) & 255, l = j >> 14;
    SWB[j] = f2bf(sw[(l * 256 + o) * 64 + c]);
  }
  int k2 = i - 196608;
  if (k2 >= 0 && k2 < 65536) WMX[k2] = f2bf(gcw[k2]);  // identical index order
  int m = i - 262144;
  if (m >= 0 && m < 131072) {  // W1T[o][e]
    int e = m & 511, o = m >> 9;
    W1T[m] = o1w[e * 256 + o];
  }
  int sp = i - 393216;
  if (sp >= 0 && sp < 524288) {  // SPD[s][n512][m512] zero-padded bf16
    int mm = sp & 511, n = (sp >> 9) & 511, s = sp >> 18;
    float v = (n < NPT && mm < NPT) ? sup[(size_t)s * NPT * NPT + (size_t)n * NPT + mm] : 0.f;
    SPD[sp] = f2bf(v);
  }
  int q = i - 917504;
  if (q >= 0 && q < 192) STP[q] = (q >= 64 && q < 128) ? 1.f : 0.f;  // identity BN layer 0
  int w0 = i - 917696;
  if (w0 >= 0 && w0 < 8192) {  // layer-0 folded weights = raw weights
    int k = w0 & 127, cp = w0 >> 7;
    int tap = k >> 6, c = k & 63;
    int g = (cp * 64 + c) * 2 + tap;
    WFP[w0] = f2bf(fw[g]);
    WGP[w0] = f2bf(gw[g]);
  }
  int b0 = i - 925888;
  if (b0 >= 0 && b0 < 128) {
    if (b0 < 64) BFP[b0] = fbias[b0];
    else BGP[b0 - 64] = gbias[b0 - 64];
  }
}

// ---------------- enter: [B,12,N,2] -> Xbf[t][b][n][c] (n-major), t=0 left-pad ----------------
__global__ void k_enter(const float* __restrict__ in, const float* __restrict__ ew,
                        const float* __restrict__ eb, u16* __restrict__ X) {
  size_t idx = (size_t)blockIdx.x * 256 + threadIdx.x;
  if (idx >= 13 * SLOTP) return;
  int t = (int)(idx / SLOTP);
  size_t r = idx % SLOTP;
  int c = (int)(r & 63);
  int n = (int)((r >> 6) & 511);
  int b = (int)(r >> 15);
  float v = 0.f;
  if (n < NPT) {
    v = eb[c];
    if (t > 0) {
      const float* ip = in + (((size_t)b * 12 + (t - 1)) * NPT + n) * 2;
      v += ew[c * 2] * ip[0] + ew[c * 2 + 1] * ip[1];
    }
  }
  X[idx] = f2bf(v);
}

__global__ void k_zero_sk(float* __restrict__ p) {
  size_t i = ((size_t)blockIdx.x * 256 + threadIdx.x) * 4;
  v4 z = {};
  *(v4*)&p[i] = z;
}

// ================= FUSED layer kernel: gatedconv + skip + diffusion + mix + BN =================
// grid (Tp, B), block (64,8). x buffers n-major. XOUT != XIN (ping-pong, no races).
__global__ __launch_bounds__(512) void k_fused(
    const u16* __restrict__ XIN, u16* __restrict__ XOUT,
    const u16* __restrict__ SPD,
    const u16* __restrict__ WFP, const float* __restrict__ BFP,
    const u16* __restrict__ WGP, const float* __restrict__ BGP,
    const u16* __restrict__ SWl, const float* __restrict__ sb, float* __restrict__ SK,
    const u16* __restrict__ WMXl, const float* __restrict__ gb,
    const float* __restrict__ STP, float* __restrict__ PSUM,
    int d, int Tp, int dodiff) {
  __shared__ u16 SH[65536];   // 128KB: XS = SH ([c64][n512]), GS = SH+32768 ([n512][k64])
  __shared__ float sst[128];
  u16* XS = SH;
  u16* GS = SH + 32768;
  const int lane = threadIdx.x;
  const int w = threadIdx.y;
  const int tid = w * 64 + lane;
  const int t = blockIdx.x, b = blockIdx.y;
  const int lrow = lane & 15;
  const int kgrp = lane >> 4;
  const int nbase = w * 64;
  const size_t x_t  = (size_t)t * SLOTP + (size_t)b * NP * C;        // + n*C + c
  const size_t x_td = (size_t)(t + d) * SLOTP + (size_t)b * NP * C;
  if (tid < 128) sst[tid] = 0.f;

  // ---- gated conv: direct-global A-frags (X n-major), B = folded weights ----
  v4 af[4][4], ag[4][4];
#pragma unroll
  for (int a1 = 0; a1 < 4; ++a1)
#pragma unroll
    for (int a2 = 0; a2 < 4; ++a2) { af[a1][a2] = (v4){0.f,0.f,0.f,0.f}; ag[a1][a2] = (v4){0.f,0.f,0.f,0.f}; }
#pragma unroll
  for (int k0 = 0; k0 < 128; k0 += 32) {
    const int kof = k0 + kgrp * 8;
    const int tap = kof >> 6, coff = kof & 63;
    const u16* xsl = XIN + (tap ? x_td : x_t);
    bf8 Av[4];
#pragma unroll
    for (int nt = 0; nt < 4; ++nt) {
      int n = nbase + nt * 16 + lrow;
      Av[nt] = *(const bf8*)&xsl[(size_t)n * C + coff];
    }
#pragma unroll
    for (int ct = 0; ct < 4; ++ct) {
      bf8 Fw = *(const bf8*)&WFP[(ct * 16 + lrow) * 128 + kof];
      bf8 Gw = *(const bf8*)&WGP[(ct * 16 + lrow) * 128 + kof];
#pragma unroll
      for (int nt = 0; nt < 4; ++nt) {
        af[nt][ct] = __builtin_amdgcn_mfma_f32_16x16x32_bf16(Av[nt], Fw, af[nt][ct], 0, 0, 0);
        ag[nt][ct] = __builtin_amdgcn_mfma_f32_16x16x32_bf16(Av[nt], Gw, ag[nt][ct], 0, 0, 0);
      }
    }
  }
  // activation -> stage XS [cp][n] (this IS the diffmix B-operand; XA never hits global)
#pragma unroll
  for (int nt = 0; nt < 4; ++nt) {
    int n0s = nbase + nt * 16 + kgrp * 4;
#pragma unroll
    for (int ct = 0; ct < 4; ++ct) {
      int cp = ct * 16 + lrow;
      float fb = BFP[cp], gb2 = BGP[cp];
      ushort4 ov;
      ov.x = f2bf(tanhf(af[nt][ct][0] + fb) * sigm(ag[nt][ct][0] + gb2));
      ov.y = f2bf(tanhf(af[nt][ct][1] + fb) * sigm(ag[nt][ct][1] + gb2));
      ov.z = f2bf(tanhf(af[nt][ct][2] + fb) * sigm(ag[nt][ct][2] + gb2));
      ov.w = f2bf(tanhf(af[nt][ct][3] + fb) * sigm(ag[nt][ct][3] + gb2));
      *(ushort4*)&XS[swzX(cp, n0s) >> 1] = ov;
    }
  }
  __syncthreads();

  // ---- fused skip GEMM on the layer's last slice ----
  if (t == Tp - 1) {
    bf8 Bsf[4][2];
#pragma unroll
    for (int nt = 0; nt < 4; ++nt)
#pragma unroll
      for (int kk = 0; kk < 2; ++kk) {
        int n = nbase + nt * 16 + lrow;
        bf8 v;
#pragma unroll
        for (int e = 0; e < 8; ++e) {
          int c = kk * 32 + kgrp * 8 + e;
          v[e] = (short)XS[swzX(c, n) >> 1];
        }
        Bsf[nt][kk] = v;
      }
#pragma unroll 1
    for (int ot = 0; ot < 16; ++ot) {
      v4 a[4];
#pragma unroll
      for (int nt = 0; nt < 4; ++nt) a[nt] = (v4){0.f,0.f,0.f,0.f};
#pragma unroll
      for (int kk = 0; kk < 2; ++kk) {
        bf8 Aw = *(const bf8*)&SWl[(size_t)(ot * 16 + lrow) * 64 + kk * 32 + kgrp * 8];
#pragma unroll
        for (int nt = 0; nt < 4; ++nt)
          a[nt] = __builtin_amdgcn_mfma_f32_16x16x32_bf16(Bsf[nt][kk], Aw, a[nt], 0, 0, 0);
      }
      int o = ot * 16 + lrow;
      float bb = sb[o];
#pragma unroll
      for (int nt = 0; nt < 4; ++nt) {
        int n0s = nbase + nt * 16 + kgrp * 4;
        if (n0s < NPT) {
          float* dst = &SK[(size_t)o * (B * NPT) + (size_t)b * NPT + n0s];
          v4 old = *(const v4*)dst;
          *(v4*)dst = old + a[nt] + bb;
        }
      }
    }
  }
  if (!dodiff) return;

  // ---- diffusion: per-support phase1 (G_s) -> phase2 partial into acc2 ----
  v4 acc2[4][4];
#pragma unroll
  for (int a = 0; a < 4; ++a)
#pragma unroll
    for (int c2 = 0; c2 < 4; ++c2) acc2[a][c2] = (v4){0.f, 0.f, 0.f, 0.f};

#pragma unroll 1
  for (int s = 0; s < 2; ++s) {
    v4 acc[4][4];
#pragma unroll
    for (int a = 0; a < 4; ++a)
#pragma unroll
      for (int c2 = 0; c2 < 4; ++c2) acc[a][c2] = (v4){0.f, 0.f, 0.f, 0.f};
    const u16* Sb = SPD + (size_t)s * (512 * 512);
    bf8 Ac[4];
#pragma unroll
    for (int nt = 0; nt < 4; ++nt)
      Ac[nt] = *(const bf8*)&Sb[(size_t)(nbase + nt * 16 + lrow) * 512 + kgrp * 8];
#pragma unroll 1
    for (int k0 = 0; k0 < 512; k0 += 32) {
      const int kof = k0 + kgrp * 8;
      bf8 An[4];
      if (k0 + 32 < 512) {
#pragma unroll
        for (int nt = 0; nt < 4; ++nt)
          An[nt] = *(const bf8*)&Sb[(size_t)(nbase + nt * 16 + lrow) * 512 + kof + 32];
      }
      bf8 Bf[4];
#pragma unroll
      for (int ct = 0; ct < 4; ++ct)
        Bf[ct] = *(const bf8*)&XS[swzX(ct * 16 + lrow, kof) >> 1];
#pragma unroll
      for (int nt = 0; nt < 4; ++nt)
#pragma unroll
        for (int ct = 0; ct < 4; ++ct)
          acc[nt][ct] = __builtin_amdgcn_mfma_f32_16x16x32_bf16(Ac[nt], Bf[ct], acc[nt][ct], 0, 0, 0);
#pragma unroll
      for (int nt = 0; nt < 4; ++nt) Ac[nt] = An[nt];
    }
#pragma unroll
    for (int nt = 0; nt < 4; ++nt)
#pragma unroll
      for (int ct = 0; ct < 4; ++ct)
#pragma unroll
        for (int r = 0; r < 4; ++r) {
          int n = nbase + nt * 16 + kgrp * 4 + r;
          int k = ct * 16 + lrow;
          GS[swzG(n, k) >> 1] = f2bf(acc[nt][ct][r]);
        }
    __syncthreads();
#pragma unroll
    for (int k0 = 0; k0 < 64; k0 += 32) {
      const int kof = k0 + kgrp * 8;
      bf8 Af[4], Bw[4];
#pragma unroll
      for (int nt = 0; nt < 4; ++nt)
        Af[nt] = *(const bf8*)&GS[swzG(nbase + nt * 16 + lrow, kof) >> 1];
#pragma unroll
      for (int ot = 0; ot < 4; ++ot)
        Bw[ot] = *(const bf8*)&WMXl[(size_t)(ot * 16 + lrow) * 128 + s * 64 + kof];
#pragma unroll
      for (int nt = 0; nt < 4; ++nt)
#pragma unroll
        for (int ot = 0; ot < 4; ++ot)
          acc2[nt][ot] = __builtin_amdgcn_mfma_f32_16x16x32_bf16(Af[nt], Bw[ot], acc2[nt][ot], 0, 0, 0);
    }
    __syncthreads();
  }

  // ---- epilogue: stage acc2 -> NS (=GS region) as [n][o]; stream n-major rows ----
#pragma unroll
  for (int nt = 0; nt < 4; ++nt)
#pragma unroll
    for (int ot = 0; ot < 4; ++ot) {
      int o = ot * 16 + lrow;
#pragma unroll
      for (int r = 0; r < 4; ++r) {
        int n = nbase + nt * 16 + kgrp * 4 + r;
        GS[swzG(n, o) >> 1] = f2bf(acc2[nt][ot][r]);
      }
    }
  __syncthreads();

  const int cchunk = tid & 7;
  const int c0 = cchunk * 8;
  float m8[8], sc8[8], h8[8], gb8[8];
#pragma unroll
  for (int e = 0; e < 8; ++e) {
    m8[e] = STP[c0 + e];
    sc8[e] = STP[64 + c0 + e];
    h8[e] = STP[128 + c0 + e];
    gb8[e] = gb[c0 + e];
  }
  float s8[8] = {}, q8[8] = {};
#pragma unroll 1
  for (int i = 0; i < 8; ++i) {
    int idx = i * 512 + tid;
    int n = idx >> 3;
    int byte = swzG(n, c0);
    ushort4 g0 = *(const ushort4*)&GS[byte >> 1];
    ushort4 g1 = *(const ushort4*)&GS[(byte >> 1) + 4];
    const u16* rp = &XIN[x_td + (size_t)n * C + c0];
    ushort4 r0 = *(const ushort4*)rp;
    ushort4 r1 = *(const ushort4*)(rp + 4);
    float v[8];
    v[0] = bf2f(g0.x) + gb8[0] + (bf2f(r0.x) - m8[0]) * sc8[0] + h8[0];
    v[1] = bf2f(g0.y) + gb8[1] + (bf2f(r0.y) - m8[1]) * sc8[1] + h8[1];
    v[2] = bf2f(g0.z) + gb8[2] + (bf2f(r0.z) - m8[2]) * sc8[2] + h8[2];
    v[3] = bf2f(g0.w) + gb8[3] + (bf2f(r0.w) - m8[3]) * sc8[3] + h8[3];
    v[4] = bf2f(g1.x) + gb8[4] + (bf2f(r1.x) - m8[4]) * sc8[4] + h8[4];
    v[5] = bf2f(g1.y) + gb8[5] + (bf2f(r1.y) - m8[5]) * sc8[5] + h8[5];
    v[6] = bf2f(g1.z) + gb8[6] + (bf2f(r1.z) - m8[6]) * sc8[6] + h8[6];
    v[7] = bf2f(g1.w) + gb8[7] + (bf2f(r1.w) - m8[7]) * sc8[7] + h8[7];
    ushort4 s0, s1;
    s0.x = f2bf(v[0]); s0.y = f2bf(v[1]); s0.z = f2bf(v[2]); s0.w = f2bf(v[3]);
    s1.x = f2bf(v[4]); s1.y = f2bf(v[5]); s1.z = f2bf(v[6]); s1.w = f2bf(v[7]);
    u16* op = &XOUT[x_t + (size_t)n * C + c0];
    *(ushort4*)op = s0;
    *(ushort4*)(op + 4) = s1;
    if (n < NPT) {
#pragma unroll
      for (int e = 0; e < 8; ++e) { s8[e] += v[e]; q8[e] += v[e] * v[e]; }
    }
  }
  // reduce across lanes sharing cchunk (lane XOR 8,16,32), then 1 atomic set per group
#pragma unroll
  for (int off = 8; off < 64; off <<= 1) {
#pragma unroll
    for (int e = 0; e < 8; ++e) {
      s8[e] += __shfl_xor(s8[e], off, 64);
      q8[e] += __shfl_xor(q8[e], off, 64);
    }
  }
  if (lane < 8) {
#pragma unroll
    for (int e = 0; e < 8; ++e) {
      atomicAdd(&sst[c0 + e], s8[e]);
      atomicAdd(&sst[64 + c0 + e], q8[e]);
    }
  }
  __syncthreads();
  if (tid < 128) PSUM[(size_t)(blockIdx.y * gridDim.x + blockIdx.x) * 128 + tid] = sst[tid];
}

// ---------------- reduce PSUM -> BN params + build next layer's folded weights ----------------
__global__ __launch_bounds__(1024) void k_bnfin(
    const float* __restrict__ PSUM, float* __restrict__ stp,
    const float* __restrict__ gamma, const float* __restrict__ beta,
    const u16* __restrict__ WFB_nl, const u16* __restrict__ WGB_nl,
    const float* __restrict__ fb_nl, const float* __restrict__ gb_nl,
    u16* __restrict__ WFP, u16* __restrict__ WGP,
    float* __restrict__ BFP, float* __restrict__ BGP,
    int nblk, int Tp) {
  __shared__ double red[1024];
  __shared__ float sscl[64], sshm[64];
  int tid = threadIdx.x;
  int c = tid & 127;
  int ch = tid >> 7;
  double s = 0.0;
  for (int r = ch; r < nblk; r += 8) s += (double)PSUM[(size_t)r * 128 + c];
  red[tid] = s;
  __syncthreads();
  if (ch < 4) red[tid] += red[tid + 512];
  __syncthreads();
  if (ch < 2) red[tid] += red[tid + 256];
  __syncthreads();
  if (ch == 0) red[c] = red[c] + red[c + 128];
  __syncthreads();
  if (tid < 64) {
    double cnt = (double)Tp * (double)(B * NPT);
    double m = red[tid] / cnt;
    double v = red[64 + tid] / cnt - m * m;
    float mf = (float)m;
    float scl = gamma[tid] * rsqrtf((float)v + 1e-5f);
    stp[tid] = mf;
    stp[64 + tid] = scl;
    stp[128 + tid] = beta[tid];
    sscl[tid] = scl;
    sshm[tid] = beta[tid] - mf * scl;
  }
  __syncthreads();
  // folded weights for next layer: W' = W * scl[c]
  for (int i = tid; i < 16384; i += 1024) {
    int which = i >> 13, j = i & 8191;
    int cc = j & 63;
    float sc = sscl[cc];
    if (which == 0) WFP[j] = f2bf(bf2f(WFB_nl[j]) * sc);
    else            WGP[j] = f2bf(bf2f(WGB_nl[j]) * sc);
  }
  // folded biases: b' = b + sum_k shm[c(k)] * W[cp][k]
  if (tid < 128) {
    int cp = tid & 63;
    const u16* W = (tid < 64) ? WFB_nl : WGB_nl;
    float acc = (tid < 64) ? fb_nl[cp] : gb_nl[cp];
    for (int k = 0; k < 128; ++k) acc += sshm[k & 63] * bf2f(W[cp * 128 + k]);
    if (tid < 64) BFP[cp] = acc; else BGP[cp] = acc;
  }
}

// ---------------- head 1 ----------------
__global__ __launch_bounds__(256) void k_out1(const float* __restrict__ SK,
                                              const float* __restrict__ W1T,
                                              const float* __restrict__ b1,
                                              u16* __restrict__ H1) {
  __shared__ __align__(16) float ssm[32 * 64];
  __shared__ __align__(16) float wsm[32 * 64];
  const int tx = threadIdx.x, ty = threadIdx.y;
  const int tid = ty * 16 + tx;
  const int p0 = blockIdx.x * 64, e0 = blockIdx.y * 64;
  v4 acc[4] = {};
  for (int o0 = 0; o0 < SC; o0 += 32) {
    __syncthreads();
    for (int i = tid; i < 2048; i += 256) {
      int pp = i & 63, kk = i >> 6;
      ssm[i] = fmaxf(SK[(size_t)(o0 + kk) * (B * NPT) + p0 + pp], 0.f);
      wsm[i] = W1T[(size_t)(o0 + kk) * 512 + e0 + pp];
    }
    __syncthreads();
#pragma unroll
    for (int kk = 0; kk < 32; ++kk) {
      v4 sv = *(const v4*)&ssm[kk * 64 + tx * 4];
      v4 wv = *(const v4*)&wsm[kk * 64 + ty * 4];
#pragma unroll
      for (int r = 0; r < 4; ++r) acc[r] += wv[r] * sv;
    }
  }
#pragma unroll
  for (int r = 0; r < 4; ++r) {
    int e = e0 + ty * 4 + r;
    float bb = b1[e];
    size_t ob = (size_t)e * (B * NPT) + p0 + tx * 4;
#pragma unroll
    for (int q = 0; q < 4; ++q) H1[ob + q] = f2bf(fmaxf(acc[r][q] + bb, 0.f));
  }
}

// ---------------- head 2 ----------------
__global__ __launch_bounds__(256) void k_out2(const u16* __restrict__ H1,
                                              const float* __restrict__ W2,
                                              const float* __restrict__ b2,
                                              float* __restrict__ out) {
  int idx = blockIdx.x * 256 + threadIdx.x;
  if (idx >= B * PR * NPT) return;
  int n = idx % NPT;
  int p12 = (idx / NPT) % PR;
  int b = idx / (NPT * PR);
  size_t p = (size_t)b * NPT + n;
  const float* w = W2 + p12 * EC;
  float acc = b2[p12];
  for (int e = 0; e < EC; e += 4) {
    acc += w[e] * bf2f(H1[(size_t)e * (B * NPT) + p])
         + w[e + 1] * bf2f(H1[(size_t)(e + 1) * (B * NPT) + p])
         + w[e + 2] * bf2f(H1[(size_t)(e + 2) * (B * NPT) + p])
         + w[e + 3] * bf2f(H1[(size_t)(e + 3) * (B * NPT) + p]);
  }
  out[idx] = acc;
}

}  // namespace

extern "C" void kernel_launch(void* const* d_in, const int* in_sizes, int n_in,
                              void* d_out, int out_size, void* d_ws, size_t ws_size,
                              hipStream_t stream) {
  const float* inputs  = (const float*)d_in[0];
  const float* sup     = (const float*)d_in[1];
  const float* enter_w = (const float*)d_in[2];
  const float* enter_b = (const float*)d_in[3];
  const float* filt_w  = (const float*)d_in[4];
  const float* filt_b  = (const float*)d_in[5];
  const float* gate_w  = (const float*)d_in[6];
  const float* gate_b  = (const float*)d_in[7];
  const float* gconv_w = (const float*)d_in[8];
  const float* gconv_b = (const float*)d_in[9];
  const float* skip_w  = (const float*)d_in[10];
  const float* skip_b  = (const float*)d_in[11];
  const float* bn_g    = (const float*)d_in[12];
  const float* bn_b    = (const float*)d_in[13];
  const float* o1w     = (const float*)d_in[14];
  const float* o1b     = (const float*)d_in[15];
  const float* o2w     = (const float*)d_in[16];
  const float* o2b     = (const float*)d_in[17];
  (void)in_sizes; (void)n_in; (void)out_size;

  if (ws_size < WS_NEED) {
    k_debug_ws<<<1500, 256, 0, stream>>>((float*)d_out, (float)(ws_size >> 20));
    return;
  }

  char* base = (char*)d_ws;
  u16*    buf0 = (u16*)base;
  u16*    buf1 = (u16*)(base + SZ_BUF);
  float*  SK   = (float*)(base + OFF_SK);
  float*  STP  = (float*)(base + OFF_STP);
  float*  W1T  = (float*)(base + OFF_W1T);
  u16*    WMX  = (u16*)(base + OFF_WMX);
  u16*    WFB  = (u16*)(base + OFF_WFB);
  u16*    WGB  = (u16*)(base + OFF_WGB);
  u16*    SWB  = (u16*)(base + OFF_SWB);
  u16*    SPD  = (u16*)(base + OFF_SPD);
  float*  PSUM = (float*)(base + OFF_PSUM);
  u16*    WFP  = (u16*)(base + OFF_WFP);
  u16*    WGP  = (u16*)(base + OFF_WGP);
  float*  BFP  = (float*)(base + OFF_BFP);
  float*  BGP  = (float*)(base + OFF_BGP);

  k_prep<<<3618, 256, 0, stream>>>(filt_w, gate_w, skip_w, gconv_w, o1w, sup,
                                   filt_b, gate_b,
                                   WFB, WGB, SWB, WMX, W1T, SPD, STP,
                                   WFP, WGP, BFP, BGP);
  k_enter<<<(int)((13 * SLOTP) / 256), 256, 0, stream>>>(inputs, enter_w, enter_b, buf0);
  k_zero_sk<<<8000, 256, 0, stream>>>(SK);

  static const int dils[8] = {1, 2, 1, 2, 1, 2, 1, 2};
  u16* bufs[2] = {buf0, buf1};
  int T = T0;
  for (int l = 0; l < 8; ++l) {
    const int d = dils[l];
    const int Tp = T - d;
    u16* XIN  = bufs[l & 1];
    u16* XOUT = bufs[(l + 1) & 1];
    k_fused<<<dim3(Tp, B), dim3(64, 8), 0, stream>>>(
        XIN, XOUT, SPD, WFP, BFP, WGP, BGP,
        SWB + l * 16384, skip_b + l * 256, SK,
        WMX + l * 8192, gconv_b + l * 64, STP, PSUM, d, Tp, l < 7 ? 1 : 0);
    if (l < 7) {
      k_bnfin<<<1, 1024, 0, stream>>>(
          PSUM, STP, bn_g + l * 64, bn_b + l * 64,
          WFB + (l + 1) * 8192, WGB + (l + 1) * 8192,
          filt_b + (l + 1) * 64, gate_b + (l + 1) * 64,
          WFP, WGP, BFP, BGP, Tp * B, Tp);
    }
    T = Tp;
  }

  u16* H1 = buf0;  // dead after the loop (l=7 reads buf1, writes nothing)
  k_out1<<<dim3(500, 8), dim3(16, 16), 0, stream>>>(SK, W1T, o1b, H1);
  k_out2<<<1500, 256, 0, stream>>>(H1, o2w, o2b, (float*)d_out);
}